// Round 9
// baseline (127.255 us; speedup 1.0000x reference)
//
#include <hip/hip_runtime.h>

// ---------------------------------------------------------------------------
// SegformerGAT round 9 (= R8 + race fix): 4 dispatches.
//  1 fusion2b : concat GEMM(K=1024)+LN + inproj GEMM(K=256)+LN (fp32 weights
//               reg-staged, lgkm-barrier pipeline) ++ weight-convert blocks.
//  2 gemm3    : l0 GEMM -> XLR0 (R6/R7 validated).
//  3 gatgemm<4>: GAT(h=4, analytic grid adj) -> LDS A-tile -> GEMM x w_l1.
//  4 gatgemm<1>: GAT(h=1) -> A-tile -> GEMM x fp_w -> planar fp32 out.
// FIX vs R8: gatgemm K=256 path used a 3-buffer loop that staged tile t+3
// into the buffer being read in the same iteration (race). Both K now use
// the safe 2-buffer dual-barrier loop (reads drained before overwrite).
// ---------------------------------------------------------------------------

#define NNODE 4096
#define LN_EPS 1e-5f
#define LOG2E 1.4426950408889634f

typedef _Float16 half8 __attribute__((ext_vector_type(8)));
typedef _Float16 half4 __attribute__((ext_vector_type(4)));
typedef _Float16 h2 __attribute__((ext_vector_type(2)));
typedef float f32x4 __attribute__((ext_vector_type(4)));

__device__ __forceinline__ float wave_reduce_sum(float v) {
    #pragma unroll
    for (int off = 32; off > 0; off >>= 1) v += __shfl_xor(v, off, 64);
    return v;
}

__device__ __forceinline__ void gload_lds16(const void* g, void* l) {
    __builtin_amdgcn_global_load_lds(
        (const __attribute__((address_space(1))) void*)g,
        (__attribute__((address_space(3))) void*)l, 16, 0, 0);
}

template<int N> __device__ __forceinline__ void waitcnt_vm() {
    if constexpr (N <= 0)      asm volatile("s_waitcnt vmcnt(0)" ::: "memory");
    else if constexpr (N == 2) asm volatile("s_waitcnt vmcnt(2)" ::: "memory");
    else if constexpr (N == 3) asm volatile("s_waitcnt vmcnt(3)" ::: "memory");
    else if constexpr (N == 4) asm volatile("s_waitcnt vmcnt(4)" ::: "memory");
    else                       asm volatile("s_waitcnt vmcnt(8)" ::: "memory");
}
__device__ __forceinline__ void lgkm0() {
    asm volatile("s_waitcnt lgkmcnt(0)" ::: "memory");
}
__device__ __forceinline__ void barrier_raw() {
    asm volatile("s_barrier" ::: "memory");
}

// ---------------------------------------------------------------------------
// 3-buffer counted-vmcnt MFMA f16 GEMM (R6/R7 validated). OUTMODE=1 only.
// ---------------------------------------------------------------------------
template<int IT, int JT, int OUTMODE>
__global__ __launch_bounds__(256) void gemm3_k(
    const _Float16* __restrict__ A, const _Float16* __restrict__ W,
    const float* __restrict__ bias_lo, const float* __restrict__ bias_hi,
    int nsplit, void* __restrict__ Cout, int K, int N)
{
    constexpr int BM = 32 * IT, BN = 32 * JT;
    constexpr int CA = (BM * 4) / 256;
    constexpr int CB = (BN * 4) / 256;
    constexpr int L = CA + CB;
    __shared__ _Float16 ldsA[3][BM * 32];
    __shared__ _Float16 ldsB[3][BN * 32];

    const int tid = threadIdx.x;
    const int m0 = blockIdx.y * BM, n0 = blockIdx.x * BN;
    const int lane = tid & 63, w = tid >> 6;
    const int fr = lane & 15, kq = lane >> 4;
    const int sq = (kq ^ (fr & 3)) * 8;
    const int wm = (w & 1) * (16 * IT), wn = (w >> 1) * (16 * JT);

    const _Float16* aP[CA]; int aC[CA];
    #pragma unroll
    for (int i = 0; i < CA; ++i) {
        const int c = i * 256 + tid, r = c >> 2, q = (c & 3) ^ (r & 3);
        aP[i] = A + (size_t)(m0 + r) * K + q * 8;
        aC[i] = c * 8;
    }
    const _Float16* bP[CB]; int bC[CB];
    #pragma unroll
    for (int i = 0; i < CB; ++i) {
        const int c = i * 256 + tid, r = c >> 2, q = (c & 3) ^ (r & 3);
        bP[i] = W + (size_t)(n0 + r) * K + q * 8;
        bC[i] = c * 8;
    }

    f32x4 acc[IT][JT] = {};
    const int NT = K >> 5;

    #pragma unroll
    for (int i = 0; i < CA; ++i) gload_lds16(aP[i], &ldsA[0][aC[i]]);
    #pragma unroll
    for (int i = 0; i < CB; ++i) gload_lds16(bP[i], &ldsB[0][bC[i]]);
    #pragma unroll
    for (int i = 0; i < CA; ++i) gload_lds16(aP[i] + 32, &ldsA[1][aC[i]]);
    #pragma unroll
    for (int i = 0; i < CB; ++i) gload_lds16(bP[i] + 32, &ldsB[1][bC[i]]);

    int bi = 0;
    for (int t = 0; t < NT; ++t) {
        if (t + 1 < NT) waitcnt_vm<L>(); else waitcnt_vm<0>();
        barrier_raw();
        if (t + 2 < NT) {
            int nb = bi + 2; if (nb >= 3) nb -= 3;
            const int k2 = (t + 2) << 5;
            #pragma unroll
            for (int i = 0; i < CA; ++i) gload_lds16(aP[i] + k2, &ldsA[nb][aC[i]]);
            #pragma unroll
            for (int i = 0; i < CB; ++i) gload_lds16(bP[i] + k2, &ldsB[nb][bC[i]]);
        }
        half8 af[IT], bf[JT];
        #pragma unroll
        for (int i = 0; i < IT; ++i)
            af[i] = *(const half8*)&ldsA[bi][(wm + i * 16 + fr) * 32 + sq];
        #pragma unroll
        for (int j = 0; j < JT; ++j)
            bf[j] = *(const half8*)&ldsB[bi][(wn + j * 16 + fr) * 32 + sq];
        #pragma unroll
        for (int i = 0; i < IT; ++i)
            #pragma unroll
            for (int j = 0; j < JT; ++j)
                acc[i][j] = __builtin_amdgcn_mfma_f32_16x16x32_f16(
                    bf[j], af[i], acc[i][j], 0, 0, 0);    // swapped (OUTMODE=1)
        ++bi; if (bi == 3) bi = 0;
    }

    // swapped epilogue: lane&15 = m, regs = 4 consecutive n
    #pragma unroll
    for (int i = 0; i < IT; ++i) {
        const int m = m0 + wm + i * 16 + fr;
        #pragma unroll
        for (int j = 0; j < JT; ++j) {
            const int nb4 = n0 + wn + j * 16 + kq * 4;
            const float* bp = (nb4 < nsplit) ? bias_lo + nb4
                                             : bias_hi + (nb4 - nsplit);
            const float4 bv = *(const float4*)bp;
            half4 ov = {(_Float16)(acc[i][j][0] + bv.x),
                        (_Float16)(acc[i][j][1] + bv.y),
                        (_Float16)(acc[i][j][2] + bv.z),
                        (_Float16)(acc[i][j][3] + bv.w)};
            *(half4*)((_Float16*)Cout + (size_t)m * N + nb4) = ov;
        }
    }
}

// ---------------------------------------------------------------------------
// fusion2b: fusion GEMM+LN+ReLU then inproj GEMM+LN+ReLU, fp32 weights
// reg-staged (2-buffer, lgkm-only barriers so global loads fly across them).
// Blocks >= 256 convert late weights fp32->f16 (w_l0,w_l1,w_fp,att).
// ---------------------------------------------------------------------------
struct ConvTab {
    const float* src[7];
    int startblk[8];
    int nelem[7];
    int dstoff[7];
    float scale[7];
};

__global__ __launch_bounds__(512) void fusion2b_k(
    const float* __restrict__ A0, const float* __restrict__ A1,
    const float* __restrict__ W1f, const float* __restrict__ b1,
    const float* __restrict__ g1, const float* __restrict__ be1,
    const float* __restrict__ W2f, const float* __restrict__ b2,
    const float* __restrict__ g2, const float* __restrict__ be2,
    _Float16* __restrict__ out, _Float16* __restrict__ wdst, ConvTab ct)
{
    if (blockIdx.x >= 256) {            // weight-conversion role (0 LDS use)
        const int cid = blockIdx.x - 256;
        int s = 0;
        #pragma unroll
        for (int i = 1; i < 7; ++i) s += (cid >= ct.startblk[i]);
        const int e0 = (cid - ct.startblk[s]) * 2048 + threadIdx.x * 4;
        if (e0 < ct.nelem[s]) {
            const float4 v = *(const float4*)(ct.src[s] + e0);
            const float sc = ct.scale[s];
            half4 o = {(_Float16)(v.x * sc), (_Float16)(v.y * sc),
                       (_Float16)(v.z * sc), (_Float16)(v.w * sc)};
            *(half4*)(wdst + ct.dstoff[s] + e0) = o;
        }
        return;
    }

    __shared__ _Float16 lA[2][32 * 32];
    __shared__ _Float16 lB[2][256 * 32];
    __shared__ float lC[32 * 260];
    __shared__ _Float16 lH[8 * 1024];

    const int tid = threadIdx.x;
    const int m0 = blockIdx.x * 32;
    const int lane = tid & 63, w = tid >> 6;
    const int fr = lane & 15, kq = lane >> 4;
    const int sq = (kq ^ (fr & 3)) * 8;
    const int wr = (w & 1) * 16, wc = (w >> 1) * 64;
    const bool stager = (tid < 128);

    // B mapping: rows br_, +64, +128, +192; float4 #bf_ (global quad bq_, half bo_)
    const int br_ = tid >> 3, bf_ = tid & 7;
    const int bq_ = bf_ >> 1, bo_ = bf_ & 1;
    float4 pb[4];

    // A staging (stagers): natural source quad, swizzled LDS dest (R5 fix)
    const int ar = tid >> 2, aq = tid & 3;
    const int asw = (ar * 4 + (aq ^ (ar & 3))) * 8;
    float4 pa0, pa1;

    auto loadB = [&](const float* Wf, int ldw, int k0) {
        #pragma unroll
        for (int i = 0; i < 4; ++i)
            pb[i] = *(const float4*)(Wf + (size_t)(br_ + i * 64) * ldw + k0 + bf_ * 4);
    };
    auto writeB = [&](int buf) {
        #pragma unroll
        for (int i = 0; i < 4; ++i) {
            const int r = br_ + i * 64;
            half4 o = {(_Float16)pb[i].x, (_Float16)pb[i].y,
                       (_Float16)pb[i].z, (_Float16)pb[i].w};
            *(half4*)&lB[buf][(r * 4 + (bq_ ^ (r & 3))) * 8 + bo_ * 4] = o;
        }
    };
    auto loadA = [&](int k) {
        const int gk = k + aq * 8;
        const float* s = (gk < 512) ? A0 + (size_t)(m0 + ar) * 512 + gk
                                    : A1 + (size_t)(m0 + ar) * 512 + gk - 512;
        pa0 = *(const float4*)s;
        pa1 = *(const float4*)(s + 4);
    };
    auto writeA = [&](int buf) {
        half8 hv = {(_Float16)pa0.x, (_Float16)pa0.y, (_Float16)pa0.z, (_Float16)pa0.w,
                    (_Float16)pa1.x, (_Float16)pa1.y, (_Float16)pa1.z, (_Float16)pa1.w};
        *(half8*)&lA[buf][asw] = hv;
    };

    // ---- phase 1: K=1024, NT=32 ----
    f32x4 acc1[4] = {};
    if (stager) { loadA(0); writeA(0); loadA(32); }
    loadB(W1f, 1024, 0); writeB(0); loadB(W1f, 1024, 32);
    lgkm0(); barrier_raw();
    for (int t = 0; t < 32; ++t) {
        if (t + 1 < 32) { writeB((t + 1) & 1); if (stager) writeA((t + 1) & 1); }
        lgkm0(); barrier_raw();
        if (t + 2 < 32) { loadB(W1f, 1024, (t + 2) * 32); if (stager) loadA((t + 2) * 32); }
        const half8 af = *(const half8*)&lA[t & 1][(wr + fr) * 32 + sq];
        half8 bfr[4];
        #pragma unroll
        for (int j = 0; j < 4; ++j)
            bfr[j] = *(const half8*)&lB[t & 1][(wc + j * 16 + fr) * 32 + sq];
        #pragma unroll
        for (int j = 0; j < 4; ++j)
            acc1[j] = __builtin_amdgcn_mfma_f32_16x16x32_f16(af, bfr[j], acc1[j], 0, 0, 0);
        lgkm0(); barrier_raw();
    }

    // C1 (+b1) -> lC
    #pragma unroll
    for (int j = 0; j < 4; ++j) {
        const int col = wc + j * 16 + fr;
        const float bc = b1[col];
        #pragma unroll
        for (int r4 = 0; r4 < 4; ++r4)
            lC[(wr + kq * 4 + r4) * 260 + col] = acc1[j][r4] + bc;
    }
    __syncthreads();

    // LN1 + ReLU -> lH (gload-compatible swizzled tiles; R7 validated)
    {
        const float4 gv = *(const float4*)(g1 + lane * 4);
        const float4 bv = *(const float4*)(be1 + lane * 4);
        const int t2i = lane >> 3, gq = (lane >> 1) & 3, qo = (lane & 1) * 4;
        #pragma unroll
        for (int rr = 0; rr < 4; ++rr) {
            const int row = w * 4 + rr;
            const float4 v = *(const float4*)&lC[row * 260 + lane * 4];
            float s  = v.x + v.y + v.z + v.w;
            float s2 = v.x * v.x + v.y * v.y + v.z * v.z + v.w * v.w;
            s = wave_reduce_sum(s);
            s2 = wave_reduce_sum(s2);
            const float mu  = s * (1.0f / 256.0f);
            const float var = s2 * (1.0f / 256.0f) - mu * mu;
            const float rs  = rsqrtf(var + LN_EPS);
            half4 o;
            o[0] = (_Float16)fmaxf((v.x - mu) * rs * gv.x + bv.x, 0.f);
            o[1] = (_Float16)fmaxf((v.y - mu) * rs * gv.y + bv.y, 0.f);
            o[2] = (_Float16)fmaxf((v.z - mu) * rs * gv.z + bv.z, 0.f);
            o[3] = (_Float16)fmaxf((v.w - mu) * rs * gv.w + bv.w, 0.f);
            const int qslot = gq ^ (row & 3);
            *(half4*)&lH[t2i * 1024 + (row * 4 + qslot) * 8 + qo] = o;
        }
    }
    __syncthreads();

    // ---- phase 2: K=256, NT=8, A from lH ----
    f32x4 acc2[4] = {};
    loadB(W2f, 256, 0); writeB(0); loadB(W2f, 256, 32);
    lgkm0(); barrier_raw();
    for (int t = 0; t < 8; ++t) {
        if (t + 1 < 8) writeB((t + 1) & 1);
        lgkm0(); barrier_raw();
        if (t + 2 < 8) loadB(W2f, 256, (t + 2) * 32);
        const half8 af = *(const half8*)
            &lH[t * 1024 + ((wr + fr) * 4 + (kq ^ (fr & 3))) * 8];
        half8 bfr[4];
        #pragma unroll
        for (int j = 0; j < 4; ++j)
            bfr[j] = *(const half8*)&lB[t & 1][(wc + j * 16 + fr) * 32 + sq];
        #pragma unroll
        for (int j = 0; j < 4; ++j)
            acc2[j] = __builtin_amdgcn_mfma_f32_16x16x32_f16(af, bfr[j], acc2[j], 0, 0, 0);
        lgkm0(); barrier_raw();
    }

    // C2 (+b2) -> lC
    #pragma unroll
    for (int j = 0; j < 4; ++j) {
        const int col = wc + j * 16 + fr;
        const float bc = b2[col];
        #pragma unroll
        for (int r4 = 0; r4 < 4; ++r4)
            lC[(wr + kq * 4 + r4) * 260 + col] = acc2[j][r4] + bc;
    }
    __syncthreads();

    // LN2 + ReLU -> out
    {
        const float4 gv = *(const float4*)(g2 + lane * 4);
        const float4 bv = *(const float4*)(be2 + lane * 4);
        #pragma unroll
        for (int rr = 0; rr < 4; ++rr) {
            const int row = w * 4 + rr;
            const float4 v = *(const float4*)&lC[row * 260 + lane * 4];
            float s  = v.x + v.y + v.z + v.w;
            float s2 = v.x * v.x + v.y * v.y + v.z * v.z + v.w * v.w;
            s = wave_reduce_sum(s);
            s2 = wave_reduce_sum(s2);
            const float mu  = s * (1.0f / 256.0f);
            const float var = s2 * (1.0f / 256.0f) - mu * mu;
            const float rs  = rsqrtf(var + LN_EPS);
            half4 o;
            o[0] = (_Float16)fmaxf((v.x - mu) * rs * gv.x + bv.x, 0.f);
            o[1] = (_Float16)fmaxf((v.y - mu) * rs * gv.y + bv.y, 0.f);
            o[2] = (_Float16)fmaxf((v.z - mu) * rs * gv.z + bv.z, 0.f);
            o[3] = (_Float16)fmaxf((v.w - mu) * rs * gv.w + bv.w, 0.f);
            *(half4*)(out + (size_t)(m0 + row) * 256 + lane * 4) = o;
        }
    }
}

// ---------------------------------------------------------------------------
// gatgemm: per block of 32 rows: GAT (analytic 8-neighbor grid + self) into a
// padded LDS A-tile, then GEMM A(32xK) x W(512xK) -> 512 outputs.
// Both K use the safe 2-buffer dual-barrier loop: reads drained (lgkm0 +
// barrier) BEFORE the overwrite gload is issued; vmcnt(4)+barrier at top of
// t+2 guarantees every wave's stage landed before any wave reads it.
// HEADS=4: K=1024, OUTMODE=1 -> f16 [M,512]. HEADS=1: K=256, OUTMODE=2 ->
// planar fp32 [B,512,4096].
// ---------------------------------------------------------------------------
template<int HEADS, int K, int LD, int XROFF, int OUTMODE>
__global__ __launch_bounds__(512) void gatgemm_k(
    const _Float16* __restrict__ xlr, const _Float16* __restrict__ att16,
    const float* __restrict__ gbias, const _Float16* __restrict__ W,
    const float* __restrict__ bias_lo, const float* __restrict__ bias_hi,
    int nsplit, void* __restrict__ Cout)
{
    constexpr int PAD = K + 8;
    constexpr int NT = K / 32;
    __shared__ _Float16 lA[32 * PAD];
    __shared__ _Float16 lB[2][512 * 32];

    const int tid = threadIdx.x;
    const int m0 = blockIdx.x * 32;
    const int lane = tid & 63, w = tid >> 6;
    const int g = lane >> 4, li = lane & 15;

    // B staging pointers (pre-swizzled source, linear gload dest)
    const _Float16* bP[4]; int bC[4];
    #pragma unroll
    for (int i = 0; i < 4; ++i) {
        const int c = i * 512 + tid, r = c >> 2, q = (c & 3) ^ (r & 3);
        bP[i] = W + (size_t)r * K + q * 8;
        bC[i] = c * 8;
    }
    // prologue: stage B tiles 0,1 (they land while GAT phase runs)
    #pragma unroll
    for (int i = 0; i < 4; ++i) gload_lds16(bP[i], &lB[0][bC[i]]);
    #pragma unroll
    for (int i = 0; i < 4; ++i) gload_lds16(bP[i] + 32, &lB[1][bC[i]]);

    // ---- phase A: GAT for 32 rows -> lA ----
    const int rounds = (HEADS == 4) ? 4 : 1;
    for (int rr = 0; rr < rounds; ++rr) {
        const int row = (HEADS == 4) ? (w * 4 + rr) : (w * 4 + g);
        const int gi = m0 + row;
        const int node = gi & (NNODE - 1);
        const int base = gi - node;
        const int h = (HEADS == 4) ? g : 0;
        const int nr = node >> 6, nc = node & 63;
        const int co = h * 256 + li * 16;

        int sidx[9]; float msk[9];
        {
            const int drs[8] = {-1,-1,-1, 0, 0, 1, 1, 1};
            const int dcs[8] = {-1, 0, 1,-1, 1,-1, 0, 1};
            #pragma unroll
            for (int j = 0; j < 8; ++j) {
                const int rj = nr + drs[j], cj = nc + dcs[j];
                const bool v = ((unsigned)rj < 64u) & ((unsigned)cj < 64u);
                sidx[j] = v ? (rj * 64 + cj) : node;
                msk[j] = v ? 0.f : -1e30f;
            }
            sidx[8] = node; msk[8] = 0.f;
        }
        const _Float16* xp = xlr + (size_t)base * LD + co;
        const half8 xr0 = *(const half8*)(xlr + (size_t)gi * LD + XROFF + co);
        const half8 xr1 = *(const half8*)(xlr + (size_t)gi * LD + XROFF + co + 8);
        const half8 at0 = *(const half8*)(att16 + h * 256 + li * 16);
        const half8 at1 = *(const half8*)(att16 + h * 256 + li * 16 + 8);
        const h2 hz = {(_Float16)0.f, (_Float16)0.f};
        const h2 c02 = {(_Float16)0.2f, (_Float16)0.2f};

        float lg[9];
        #pragma unroll
        for (int j = 0; j < 9; ++j) {
            const half8 x0 = *(const half8*)(xp + (size_t)sidx[j] * LD);
            const half8 x1 = *(const half8*)(xp + (size_t)sidx[j] * LD + 8);
            h2 p = hz;
            #pragma unroll
            for (int k = 0; k < 4; ++k) {
                h2 e = ((const h2*)&x0)[k] + ((const h2*)&xr0)[k];
                h2 tt = __builtin_elementwise_fma(
                    __builtin_elementwise_min(e, hz), c02,
                    __builtin_elementwise_max(e, hz));
                p = __builtin_elementwise_fma(tt, ((const h2*)&at0)[k], p);
            }
            #pragma unroll
            for (int k = 0; k < 4; ++k) {
                h2 e = ((const h2*)&x1)[k] + ((const h2*)&xr1)[k];
                h2 tt = __builtin_elementwise_fma(
                    __builtin_elementwise_min(e, hz), c02,
                    __builtin_elementwise_max(e, hz));
                p = __builtin_elementwise_fma(tt, ((const h2*)&at1)[k], p);
            }
            float pl = (float)p[0] + (float)p[1];
            pl += __shfl_xor(pl, 1, 64);
            pl += __shfl_xor(pl, 2, 64);
            pl += __shfl_xor(pl, 4, 64);
            pl += __shfl_xor(pl, 8, 64);
            lg[j] = pl + msk[j];
        }
        float m = lg[0];
        #pragma unroll
        for (int j = 1; j < 9; ++j) m = fmaxf(m, lg[j]);
        float pj[9], z = 0.f;
        #pragma unroll
        for (int j = 0; j < 9; ++j) { pj[j] = __builtin_amdgcn_exp2f(lg[j] - m); z += pj[j]; }
        const float inv = __builtin_amdgcn_rcpf(z);

        float acc[16];
        #pragma unroll
        for (int k = 0; k < 16; ++k) acc[k] = 0.f;
        #pragma unroll
        for (int j = 0; j < 9; ++j) {
            const half8 x0 = *(const half8*)(xp + (size_t)sidx[j] * LD);
            const half8 x1 = *(const half8*)(xp + (size_t)sidx[j] * LD + 8);
            const float wj = pj[j];
            #pragma unroll
            for (int k = 0; k < 8; ++k) acc[k]     += wj * (float)x0[k];
            #pragma unroll
            for (int k = 0; k < 8; ++k) acc[8 + k] += wj * (float)x1[k];
        }
        float bv[16];
        #pragma unroll
        for (int q = 0; q < 4; ++q) {
            const float4 b4 = *(const float4*)(gbias + h * 256 + li * 16 + q * 4);
            bv[q * 4 + 0] = b4.x; bv[q * 4 + 1] = b4.y;
            bv[q * 4 + 2] = b4.z; bv[q * 4 + 3] = b4.w;
        }
        half8 o0, o1;
        #pragma unroll
        for (int k = 0; k < 8; ++k) o0[k] = (_Float16)fmaxf(acc[k] * inv + bv[k], 0.f);
        #pragma unroll
        for (int k = 0; k < 8; ++k) o1[k] = (_Float16)fmaxf(acc[8 + k] * inv + bv[8 + k], 0.f);
        *(half8*)&lA[row * PAD + co] = o0;
        *(half8*)&lA[row * PAD + co + 8] = o1;
    }
    __syncthreads();    // publish lA (full drain; B tiles 0,1 long landed)

    // ---- phase B: GEMM 32 x 512 x K.  8 waves: 2 rows x 64 cols each ----
    const int fr = lane & 15, kq = lane >> 4;
    const int sq = (kq ^ (fr & 3)) * 8;
    const int wc = w * 64;
    f32x4 acc[2][4] = {};

    for (int t = 0; t < NT; ++t) {
        if (t + 1 < NT) waitcnt_vm<4>(); else waitcnt_vm<0>();
        barrier_raw();
        half8 af[2]; half8 bfr[4];
        #pragma unroll
        for (int i = 0; i < 2; ++i)
            af[i] = *(const half8*)&lA[(i * 16 + fr) * PAD + t * 32 + kq * 8];
        #pragma unroll
        for (int j = 0; j < 4; ++j)
            bfr[j] = *(const half8*)&lB[t & 1][(wc + j * 16 + fr) * 32 + sq];
        lgkm0(); barrier_raw();   // all waves' reads of lB[t&1] complete
        if (t + 2 < NT) {
            #pragma unroll
            for (int i = 0; i < 4; ++i)
                gload_lds16(bP[i] + (t + 2) * 32, &lB[t & 1][bC[i]]);
        }
        #pragma unroll
        for (int i = 0; i < 2; ++i)
            #pragma unroll
            for (int j = 0; j < 4; ++j) {
                if (OUTMODE == 1)
                    acc[i][j] = __builtin_amdgcn_mfma_f32_16x16x32_f16(
                        bfr[j], af[i], acc[i][j], 0, 0, 0);
                else
                    acc[i][j] = __builtin_amdgcn_mfma_f32_16x16x32_f16(
                        af[i], bfr[j], acc[i][j], 0, 0, 0);
            }
    }

    if (OUTMODE == 1) {
        // swapped: m from fr, n from kq*4 -> half4 stores to [8192][512]
        #pragma unroll
        for (int i = 0; i < 2; ++i) {
            const int m = m0 + i * 16 + fr;
            #pragma unroll
            for (int j = 0; j < 4; ++j) {
                const int nb4 = wc + j * 16 + kq * 4;
                const float* bp = (nb4 < nsplit) ? bias_lo + nb4
                                                 : bias_hi + (nb4 - nsplit);
                const float4 bvv = *(const float4*)bp;
                half4 ov = {(_Float16)(acc[i][j][0] + bvv.x),
                            (_Float16)(acc[i][j][1] + bvv.y),
                            (_Float16)(acc[i][j][2] + bvv.z),
                            (_Float16)(acc[i][j][3] + bvv.w)};
                *(half4*)((_Float16*)Cout + (size_t)m * 512 + nb4) = ov;
            }
        }
    } else {
        // normal: col from fr, rows from kq*4 -> float4 along nodes (planar)
        #pragma unroll
        for (int j = 0; j < 4; ++j) {
            const int col = wc + j * 16 + fr;
            const float bc = bias_lo[col];
            #pragma unroll
            for (int i = 0; i < 2; ++i) {
                const int mrun = m0 + i * 16 + kq * 4;
                const int b = mrun >> 12, node = mrun & 4095;
                float4 ov = {acc[i][j][0] + bc, acc[i][j][1] + bc,
                             acc[i][j][2] + bc, acc[i][j][3] + bc};
                *(float4*)((float*)Cout + ((size_t)(b * 512 + col)) * 4096 + node) = ov;
            }
        }
    }
}

// ---------------------------------------------------------------------------
extern "C" void kernel_launch(void* const* d_in, const int* in_sizes, int n_in,
                              void* d_out, int out_size, void* d_ws, size_t ws_size,
                              hipStream_t stream)
{
    const float* rgb       = (const float*)d_in[0];
    const float* xm        = (const float*)d_in[1];
    const float* fusion_w  = (const float*)d_in[3];
    const float* fusion_b  = (const float*)d_in[4];
    const float* fusion_g  = (const float*)d_in[5];
    const float* fusion_be = (const float*)d_in[6];
    const float* inproj_w  = (const float*)d_in[7];
    const float* inproj_b  = (const float*)d_in[8];
    const float* norm_g    = (const float*)d_in[9];
    const float* norm_b    = (const float*)d_in[10];
    const float* l0_wl     = (const float*)d_in[11];
    const float* l0_bl     = (const float*)d_in[12];
    const float* l0_wr     = (const float*)d_in[13];
    const float* l0_br     = (const float*)d_in[14];
    const float* l0_att    = (const float*)d_in[15];
    const float* l0_bias   = (const float*)d_in[16];
    const float* l1_wl     = (const float*)d_in[17];
    const float* l1_bl     = (const float*)d_in[18];
    const float* l1_wr     = (const float*)d_in[19];
    const float* l1_br     = (const float*)d_in[20];
    const float* l1_att    = (const float*)d_in[21];
    const float* l1_bias   = (const float*)d_in[22];
    const float* fp_w      = (const float*)d_in[23];
    const float* fp_b      = (const float*)d_in[24];

    // workspace
    char* ws = (char*)d_ws;
    _Float16* Wf16 = (_Float16*)ws;                  // packed f16 weights+att
    _Float16* H1   = (_Float16*)(ws + 4194304);      //  4 MB [8192][256]
    _Float16* XLR0 = (_Float16*)(ws + 8388608);      // 32 MB [8192][2048]
    _Float16* XLR1 = (_Float16*)(ws + 41943040);     //  8 MB [8192][512]

    _Float16* w_l0   = Wf16 + 327680;    // [2048][256] (wl|wr)
    _Float16* w_l1   = Wf16 + 851968;    // [512][1024] (wl|wr)
    _Float16* w_fp   = Wf16 + 1376256;   // [512][256]
    _Float16* att0_h = Wf16 + 1507328;   // [4][256] * log2e
    _Float16* att1_h = Wf16 + 1508352;   // [1][256] * log2e

    ConvTab ct;
    const float* srcs[7] = {l0_wl, l0_wr, l1_wl, l1_wr, fp_w, l0_att, l1_att};
    const int nel[7]  = {262144, 262144, 262144, 262144, 131072, 1024, 256};
    const int doff[7] = {327680, 589824, 851968, 1114112, 1376256, 1507328, 1508352};
    const int sblk[8] = {0, 128, 256, 384, 512, 576, 577, 578};
    for (int i = 0; i < 7; ++i) {
        ct.src[i] = srcs[i]; ct.nelem[i] = nel[i]; ct.dstoff[i] = doff[i];
        ct.scale[i] = (i >= 5) ? LOG2E : 1.0f;
    }
    for (int i = 0; i < 8; ++i) ct.startblk[i] = sblk[i];

    // 1: fusion + inproj (+ weight conversion) -> H1, Wf16
    fusion2b_k<<<834, 512, 0, stream>>>(
        rgb, xm, fusion_w, fusion_b, fusion_g, fusion_be,
        inproj_w, inproj_b, norm_g, norm_b, H1, Wf16, ct);

    // 2: l0 GEMM -> XLR0 (xl|xr)
    gemm3_k<4, 4, 1><<<dim3(16, 64), 256, 0, stream>>>(
        H1, w_l0, l0_bl, l0_br, 1024, XLR0, 256, 2048);

    // 3: gat(h=4) + l1 GEMM -> XLR1
    gatgemm_k<4, 1024, 2048, 1024, 1><<<256, 512, 0, stream>>>(
        XLR0, att0_h, l0_bias, w_l1, l1_bl, l1_br, 256, XLR1);

    // 4: gat(h=1) + final GEMM -> planar [2,512,4096] fp32
    gatgemm_k<1, 256, 512, 256, 2><<<256, 512, 0, stream>>>(
        XLR1, att1_h, l1_bias, w_fp, fp_b, fp_b, 512, d_out);
}

// Round 10
// 121.257 us; speedup vs baseline: 1.0495x; 1.0495x over previous
//
#include <hip/hip_runtime.h>

// ---------------------------------------------------------------------------
// SegformerGAT round 10: un-fuse R9's gatgemm (1 block/CU occupancy trap) ->
// 6 dispatches:
//  1 fusion2b : concat GEMM+LN + inproj GEMM+LN (++ weight-convert blocks)
//  2 gemm3    : l0 GEMM -> XLR0
//  3 gat4<4>  : register-resident GAT (xl of all 9 neighbors held in VGPRs,
//               single-pass, no LDS, 256-thr blocks) -> GO0
//  4 gemm3    : l1 GEMM -> XLR1
//  5 gat4<1>  : -> GO1
//  6 gemm3    : final -> planar fp32 out
// ---------------------------------------------------------------------------

#define NNODE 4096
#define LN_EPS 1e-5f
#define LOG2E 1.4426950408889634f

typedef _Float16 half8 __attribute__((ext_vector_type(8)));
typedef _Float16 half4 __attribute__((ext_vector_type(4)));
typedef _Float16 h2 __attribute__((ext_vector_type(2)));
typedef float f32x4 __attribute__((ext_vector_type(4)));

__device__ __forceinline__ float wave_reduce_sum(float v) {
    #pragma unroll
    for (int off = 32; off > 0; off >>= 1) v += __shfl_xor(v, off, 64);
    return v;
}

__device__ __forceinline__ void gload_lds16(const void* g, void* l) {
    __builtin_amdgcn_global_load_lds(
        (const __attribute__((address_space(1))) void*)g,
        (__attribute__((address_space(3))) void*)l, 16, 0, 0);
}

template<int N> __device__ __forceinline__ void waitcnt_vm() {
    if constexpr (N <= 0)      asm volatile("s_waitcnt vmcnt(0)" ::: "memory");
    else if constexpr (N == 2) asm volatile("s_waitcnt vmcnt(2)" ::: "memory");
    else if constexpr (N == 3) asm volatile("s_waitcnt vmcnt(3)" ::: "memory");
    else if constexpr (N == 4) asm volatile("s_waitcnt vmcnt(4)" ::: "memory");
    else                       asm volatile("s_waitcnt vmcnt(8)" ::: "memory");
}
__device__ __forceinline__ void lgkm0() {
    asm volatile("s_waitcnt lgkmcnt(0)" ::: "memory");
}
__device__ __forceinline__ void barrier_raw() {
    asm volatile("s_barrier" ::: "memory");
}

// ---------------------------------------------------------------------------
// 3-buffer counted-vmcnt MFMA f16 GEMM (R6/R7/R9 validated).
// OUTMODE: 1 = f16 [M,N] (swapped mfma); 2 = fp32 planar [B,N,4096].
// ---------------------------------------------------------------------------
template<int IT, int JT, int OUTMODE>
__global__ __launch_bounds__(256) void gemm3_k(
    const _Float16* __restrict__ A, const _Float16* __restrict__ W,
    const float* __restrict__ bias_lo, const float* __restrict__ bias_hi,
    int nsplit, void* __restrict__ Cout, int K, int N)
{
    constexpr int BM = 32 * IT, BN = 32 * JT;
    constexpr int CA = (BM * 4) / 256;
    constexpr int CB = (BN * 4) / 256;
    constexpr int L = CA + CB;
    __shared__ _Float16 ldsA[3][BM * 32];
    __shared__ _Float16 ldsB[3][BN * 32];

    const int tid = threadIdx.x;
    const int m0 = blockIdx.y * BM, n0 = blockIdx.x * BN;
    const int lane = tid & 63, w = tid >> 6;
    const int fr = lane & 15, kq = lane >> 4;
    const int sq = (kq ^ (fr & 3)) * 8;
    const int wm = (w & 1) * (16 * IT), wn = (w >> 1) * (16 * JT);

    const _Float16* aP[CA]; int aC[CA];
    #pragma unroll
    for (int i = 0; i < CA; ++i) {
        const int c = i * 256 + tid, r = c >> 2, q = (c & 3) ^ (r & 3);
        aP[i] = A + (size_t)(m0 + r) * K + q * 8;
        aC[i] = c * 8;
    }
    const _Float16* bP[CB]; int bC[CB];
    #pragma unroll
    for (int i = 0; i < CB; ++i) {
        const int c = i * 256 + tid, r = c >> 2, q = (c & 3) ^ (r & 3);
        bP[i] = W + (size_t)(n0 + r) * K + q * 8;
        bC[i] = c * 8;
    }

    f32x4 acc[IT][JT] = {};
    const int NT = K >> 5;

    #pragma unroll
    for (int i = 0; i < CA; ++i) gload_lds16(aP[i], &ldsA[0][aC[i]]);
    #pragma unroll
    for (int i = 0; i < CB; ++i) gload_lds16(bP[i], &ldsB[0][bC[i]]);
    #pragma unroll
    for (int i = 0; i < CA; ++i) gload_lds16(aP[i] + 32, &ldsA[1][aC[i]]);
    #pragma unroll
    for (int i = 0; i < CB; ++i) gload_lds16(bP[i] + 32, &ldsB[1][bC[i]]);

    int bi = 0;
    for (int t = 0; t < NT; ++t) {
        if (t + 1 < NT) waitcnt_vm<L>(); else waitcnt_vm<0>();
        barrier_raw();
        if (t + 2 < NT) {
            int nb = bi + 2; if (nb >= 3) nb -= 3;
            const int k2 = (t + 2) << 5;
            #pragma unroll
            for (int i = 0; i < CA; ++i) gload_lds16(aP[i] + k2, &ldsA[nb][aC[i]]);
            #pragma unroll
            for (int i = 0; i < CB; ++i) gload_lds16(bP[i] + k2, &ldsB[nb][bC[i]]);
        }
        half8 af[IT], bf[JT];
        #pragma unroll
        for (int i = 0; i < IT; ++i)
            af[i] = *(const half8*)&ldsA[bi][(wm + i * 16 + fr) * 32 + sq];
        #pragma unroll
        for (int j = 0; j < JT; ++j)
            bf[j] = *(const half8*)&ldsB[bi][(wn + j * 16 + fr) * 32 + sq];
        #pragma unroll
        for (int i = 0; i < IT; ++i)
            #pragma unroll
            for (int j = 0; j < JT; ++j) {
                if (OUTMODE == 1)
                    acc[i][j] = __builtin_amdgcn_mfma_f32_16x16x32_f16(
                        bf[j], af[i], acc[i][j], 0, 0, 0);
                else
                    acc[i][j] = __builtin_amdgcn_mfma_f32_16x16x32_f16(
                        af[i], bf[j], acc[i][j], 0, 0, 0);
            }
        ++bi; if (bi == 3) bi = 0;
    }

    if (OUTMODE == 1) {
        // swapped: lane&15 = m, regs = 4 consecutive n
        #pragma unroll
        for (int i = 0; i < IT; ++i) {
            const int m = m0 + wm + i * 16 + fr;
            #pragma unroll
            for (int j = 0; j < JT; ++j) {
                const int nb4 = n0 + wn + j * 16 + kq * 4;
                const float* bp = (nb4 < nsplit) ? bias_lo + nb4
                                                 : bias_hi + (nb4 - nsplit);
                const float4 bv = *(const float4*)bp;
                half4 ov = {(_Float16)(acc[i][j][0] + bv.x),
                            (_Float16)(acc[i][j][1] + bv.y),
                            (_Float16)(acc[i][j][2] + bv.z),
                            (_Float16)(acc[i][j][3] + bv.w)};
                *(half4*)((_Float16*)Cout + (size_t)m * N + nb4) = ov;
            }
        }
    } else {
        // planar [B, N, 4096], float4 along node (m) dim
        #pragma unroll
        for (int j = 0; j < JT; ++j) {
            const int col = n0 + wn + j * 16 + fr;
            const float bc = (col < nsplit) ? bias_lo[col] : bias_hi[col - nsplit];
            #pragma unroll
            for (int i = 0; i < IT; ++i) {
                const int mrun = m0 + wm + i * 16 + kq * 4;
                const int b = mrun >> 12, node = mrun & 4095;
                float4 ov = {acc[i][j][0] + bc, acc[i][j][1] + bc,
                             acc[i][j][2] + bc, acc[i][j][3] + bc};
                *(float4*)((float*)Cout + ((size_t)(b * N + col)) * 4096 + node) = ov;
            }
        }
    }
}

// ---------------------------------------------------------------------------
// fusion2b (R9 validated): fusion GEMM+LN then inproj GEMM+LN, fp32 weights
// reg-staged; blocks >= 256 convert late weights fp32->f16.
// ---------------------------------------------------------------------------
struct ConvTab {
    const float* src[7];
    int startblk[8];
    int nelem[7];
    int dstoff[7];
    float scale[7];
};

__global__ __launch_bounds__(512) void fusion2b_k(
    const float* __restrict__ A0, const float* __restrict__ A1,
    const float* __restrict__ W1f, const float* __restrict__ b1,
    const float* __restrict__ g1, const float* __restrict__ be1,
    const float* __restrict__ W2f, const float* __restrict__ b2,
    const float* __restrict__ g2, const float* __restrict__ be2,
    _Float16* __restrict__ out, _Float16* __restrict__ wdst, ConvTab ct)
{
    if (blockIdx.x >= 256) {            // weight-conversion role
        const int cid = blockIdx.x - 256;
        int s = 0;
        #pragma unroll
        for (int i = 1; i < 7; ++i) s += (cid >= ct.startblk[i]);
        const int e0 = (cid - ct.startblk[s]) * 2048 + threadIdx.x * 4;
        if (e0 < ct.nelem[s]) {
            const float4 v = *(const float4*)(ct.src[s] + e0);
            const float sc = ct.scale[s];
            half4 o = {(_Float16)(v.x * sc), (_Float16)(v.y * sc),
                       (_Float16)(v.z * sc), (_Float16)(v.w * sc)};
            *(half4*)(wdst + ct.dstoff[s] + e0) = o;
        }
        return;
    }

    __shared__ _Float16 lA[2][32 * 32];
    __shared__ _Float16 lB[2][256 * 32];
    __shared__ float lC[32 * 260];
    __shared__ _Float16 lH[8 * 1024];

    const int tid = threadIdx.x;
    const int m0 = blockIdx.x * 32;
    const int lane = tid & 63, w = tid >> 6;
    const int fr = lane & 15, kq = lane >> 4;
    const int sq = (kq ^ (fr & 3)) * 8;
    const int wr = (w & 1) * 16, wc = (w >> 1) * 64;
    const bool stager = (tid < 128);

    const int br_ = tid >> 3, bf_ = tid & 7;
    const int bq_ = bf_ >> 1, bo_ = bf_ & 1;
    float4 pb[4];

    const int ar = tid >> 2, aq = tid & 3;
    const int asw = (ar * 4 + (aq ^ (ar & 3))) * 8;
    float4 pa0, pa1;

    auto loadB = [&](const float* Wf, int ldw, int k0) {
        #pragma unroll
        for (int i = 0; i < 4; ++i)
            pb[i] = *(const float4*)(Wf + (size_t)(br_ + i * 64) * ldw + k0 + bf_ * 4);
    };
    auto writeB = [&](int buf) {
        #pragma unroll
        for (int i = 0; i < 4; ++i) {
            const int r = br_ + i * 64;
            half4 o = {(_Float16)pb[i].x, (_Float16)pb[i].y,
                       (_Float16)pb[i].z, (_Float16)pb[i].w};
            *(half4*)&lB[buf][(r * 4 + (bq_ ^ (r & 3))) * 8 + bo_ * 4] = o;
        }
    };
    auto loadA = [&](int k) {
        const int gk = k + aq * 8;
        const float* s = (gk < 512) ? A0 + (size_t)(m0 + ar) * 512 + gk
                                    : A1 + (size_t)(m0 + ar) * 512 + gk - 512;
        pa0 = *(const float4*)s;
        pa1 = *(const float4*)(s + 4);
    };
    auto writeA = [&](int buf) {
        half8 hv = {(_Float16)pa0.x, (_Float16)pa0.y, (_Float16)pa0.z, (_Float16)pa0.w,
                    (_Float16)pa1.x, (_Float16)pa1.y, (_Float16)pa1.z, (_Float16)pa1.w};
        *(half8*)&lA[buf][asw] = hv;
    };

    // ---- phase 1: K=1024, NT=32 ----
    f32x4 acc1[4] = {};
    if (stager) { loadA(0); writeA(0); loadA(32); }
    loadB(W1f, 1024, 0); writeB(0); loadB(W1f, 1024, 32);
    lgkm0(); barrier_raw();
    for (int t = 0; t < 32; ++t) {
        if (t + 1 < 32) { writeB((t + 1) & 1); if (stager) writeA((t + 1) & 1); }
        lgkm0(); barrier_raw();
        if (t + 2 < 32) { loadB(W1f, 1024, (t + 2) * 32); if (stager) loadA((t + 2) * 32); }
        const half8 af = *(const half8*)&lA[t & 1][(wr + fr) * 32 + sq];
        half8 bfr[4];
        #pragma unroll
        for (int j = 0; j < 4; ++j)
            bfr[j] = *(const half8*)&lB[t & 1][(wc + j * 16 + fr) * 32 + sq];
        #pragma unroll
        for (int j = 0; j < 4; ++j)
            acc1[j] = __builtin_amdgcn_mfma_f32_16x16x32_f16(af, bfr[j], acc1[j], 0, 0, 0);
        lgkm0(); barrier_raw();
    }

    #pragma unroll
    for (int j = 0; j < 4; ++j) {
        const int col = wc + j * 16 + fr;
        const float bc = b1[col];
        #pragma unroll
        for (int r4 = 0; r4 < 4; ++r4)
            lC[(wr + kq * 4 + r4) * 260 + col] = acc1[j][r4] + bc;
    }
    __syncthreads();

    {   // LN1 + ReLU -> lH
        const float4 gv = *(const float4*)(g1 + lane * 4);
        const float4 bv = *(const float4*)(be1 + lane * 4);
        const int t2i = lane >> 3, gq = (lane >> 1) & 3, qo = (lane & 1) * 4;
        #pragma unroll
        for (int rr = 0; rr < 4; ++rr) {
            const int row = w * 4 + rr;
            const float4 v = *(const float4*)&lC[row * 260 + lane * 4];
            float s  = v.x + v.y + v.z + v.w;
            float s2 = v.x * v.x + v.y * v.y + v.z * v.z + v.w * v.w;
            s = wave_reduce_sum(s);
            s2 = wave_reduce_sum(s2);
            const float mu  = s * (1.0f / 256.0f);
            const float var = s2 * (1.0f / 256.0f) - mu * mu;
            const float rs  = rsqrtf(var + LN_EPS);
            half4 o;
            o[0] = (_Float16)fmaxf((v.x - mu) * rs * gv.x + bv.x, 0.f);
            o[1] = (_Float16)fmaxf((v.y - mu) * rs * gv.y + bv.y, 0.f);
            o[2] = (_Float16)fmaxf((v.z - mu) * rs * gv.z + bv.z, 0.f);
            o[3] = (_Float16)fmaxf((v.w - mu) * rs * gv.w + bv.w, 0.f);
            const int qslot = gq ^ (row & 3);
            *(half4*)&lH[t2i * 1024 + (row * 4 + qslot) * 8 + qo] = o;
        }
    }
    __syncthreads();

    // ---- phase 2: K=256, NT=8, A from lH ----
    f32x4 acc2[4] = {};
    loadB(W2f, 256, 0); writeB(0); loadB(W2f, 256, 32);
    lgkm0(); barrier_raw();
    for (int t = 0; t < 8; ++t) {
        if (t + 1 < 8) writeB((t + 1) & 1);
        lgkm0(); barrier_raw();
        if (t + 2 < 8) loadB(W2f, 256, (t + 2) * 32);
        const half8 af = *(const half8*)
            &lH[t * 1024 + ((wr + fr) * 4 + (kq ^ (fr & 3))) * 8];
        half8 bfr[4];
        #pragma unroll
        for (int j = 0; j < 4; ++j)
            bfr[j] = *(const half8*)&lB[t & 1][(wc + j * 16 + fr) * 32 + sq];
        #pragma unroll
        for (int j = 0; j < 4; ++j)
            acc2[j] = __builtin_amdgcn_mfma_f32_16x16x32_f16(af, bfr[j], acc2[j], 0, 0, 0);
        lgkm0(); barrier_raw();
    }

    #pragma unroll
    for (int j = 0; j < 4; ++j) {
        const int col = wc + j * 16 + fr;
        const float bc = b2[col];
        #pragma unroll
        for (int r4 = 0; r4 < 4; ++r4)
            lC[(wr + kq * 4 + r4) * 260 + col] = acc2[j][r4] + bc;
    }
    __syncthreads();

    {   // LN2 + ReLU -> out
        const float4 gv = *(const float4*)(g2 + lane * 4);
        const float4 bv = *(const float4*)(be2 + lane * 4);
        #pragma unroll
        for (int rr = 0; rr < 4; ++rr) {
            const int row = w * 4 + rr;
            const float4 v = *(const float4*)&lC[row * 260 + lane * 4];
            float s  = v.x + v.y + v.z + v.w;
            float s2 = v.x * v.x + v.y * v.y + v.z * v.z + v.w * v.w;
            s = wave_reduce_sum(s);
            s2 = wave_reduce_sum(s2);
            const float mu  = s * (1.0f / 256.0f);
            const float var = s2 * (1.0f / 256.0f) - mu * mu;
            const float rs  = rsqrtf(var + LN_EPS);
            half4 o;
            o[0] = (_Float16)fmaxf((v.x - mu) * rs * gv.x + bv.x, 0.f);
            o[1] = (_Float16)fmaxf((v.y - mu) * rs * gv.y + bv.y, 0.f);
            o[2] = (_Float16)fmaxf((v.z - mu) * rs * gv.z + bv.z, 0.f);
            o[3] = (_Float16)fmaxf((v.w - mu) * rs * gv.w + bv.w, 0.f);
            *(half4*)(out + (size_t)(m0 + row) * 256 + lane * 4) = o;
        }
    }
}

// ---------------------------------------------------------------------------
// gat4: register-resident GAT, no LDS, 256-thr blocks, single xl pass.
// Wave = 4 groups of 16 lanes. HEADS=4: wave = 1 row, groups = heads.
// HEADS=1: wave = 4 rows. All 9 neighbor xl slices + xr loaded once into
// VGPRs; logits (4-stage group shfl), softmax (log2-domain att), weighted
// sum, +bias +ReLU, store.
// ---------------------------------------------------------------------------
template<int HEADS, int LD, int XROFF, int OC>
__global__ __launch_bounds__(256) void gat4_k(
    const _Float16* __restrict__ xlr, const _Float16* __restrict__ att16,
    const float* __restrict__ bias, _Float16* __restrict__ out)
{
    const int tid = threadIdx.x, wv = tid >> 6, lane = tid & 63;
    const int g = lane >> 4, li = lane & 15;
    const int wid = blockIdx.x * 4 + wv;
    const int gi = (HEADS == 4) ? wid : wid * 4 + g;
    const int h  = (HEADS == 4) ? g : 0;
    const int node = gi & (NNODE - 1);
    const int base = gi - node;
    const int nr = node >> 6, nc = node & 63;
    const int co = h * 256 + li * 16;

    int sidx[9]; float msk[9];
    {
        const int drs[8] = {-1,-1,-1, 0, 0, 1, 1, 1};
        const int dcs[8] = {-1, 0, 1,-1, 1,-1, 0, 1};
        #pragma unroll
        for (int j = 0; j < 8; ++j) {
            const int rj = nr + drs[j], cj = nc + dcs[j];
            const bool v = ((unsigned)rj < 64u) & ((unsigned)cj < 64u);
            sidx[j] = v ? (rj * 64 + cj) : node;
            msk[j] = v ? 0.f : -1e30f;
        }
        sidx[8] = node; msk[8] = 0.f;
    }

    const _Float16* xp = xlr + (size_t)base * LD + co;

    // load ALL xl slices + xr + att up front (independent loads, one wait)
    half8 x0[9], x1[9];
    #pragma unroll
    for (int j = 0; j < 9; ++j) {
        x0[j] = *(const half8*)(xp + (size_t)sidx[j] * LD);
        x1[j] = *(const half8*)(xp + (size_t)sidx[j] * LD + 8);
    }
    const half8 xr0 = *(const half8*)(xlr + (size_t)gi * LD + XROFF + co);
    const half8 xr1 = *(const half8*)(xlr + (size_t)gi * LD + XROFF + co + 8);
    const half8 at0 = *(const half8*)(att16 + h * 256 + li * 16);
    const half8 at1 = *(const half8*)(att16 + h * 256 + li * 16 + 8);
    const h2 hz = {(_Float16)0.f, (_Float16)0.f};
    const h2 c02 = {(_Float16)0.2f, (_Float16)0.2f};

    float lg[9];
    #pragma unroll
    for (int j = 0; j < 9; ++j) {
        h2 p = hz;
        #pragma unroll
        for (int k = 0; k < 4; ++k) {
            h2 e = ((const h2*)&x0[j])[k] + ((const h2*)&xr0)[k];
            h2 tt = __builtin_elementwise_fma(
                __builtin_elementwise_min(e, hz), c02,
                __builtin_elementwise_max(e, hz));
            p = __builtin_elementwise_fma(tt, ((const h2*)&at0)[k], p);
        }
        #pragma unroll
        for (int k = 0; k < 4; ++k) {
            h2 e = ((const h2*)&x1[j])[k] + ((const h2*)&xr1)[k];
            h2 tt = __builtin_elementwise_fma(
                __builtin_elementwise_min(e, hz), c02,
                __builtin_elementwise_max(e, hz));
            p = __builtin_elementwise_fma(tt, ((const h2*)&at1)[k], p);
        }
        float pl = (float)p[0] + (float)p[1];
        pl += __shfl_xor(pl, 1, 64);
        pl += __shfl_xor(pl, 2, 64);
        pl += __shfl_xor(pl, 4, 64);
        pl += __shfl_xor(pl, 8, 64);
        lg[j] = pl + msk[j];                 // log2-domain logits
    }

    float m = lg[0];
    #pragma unroll
    for (int j = 1; j < 9; ++j) m = fmaxf(m, lg[j]);
    float pj[9], z = 0.f;
    #pragma unroll
    for (int j = 0; j < 9; ++j) { pj[j] = __builtin_amdgcn_exp2f(lg[j] - m); z += pj[j]; }
    const float inv = __builtin_amdgcn_rcpf(z);

    float acc[16];
    #pragma unroll
    for (int k = 0; k < 16; ++k) acc[k] = 0.f;
    #pragma unroll
    for (int j = 0; j < 9; ++j) {
        const float wj = pj[j];
        #pragma unroll
        for (int k = 0; k < 8; ++k) acc[k]     += wj * (float)x0[j][k];
        #pragma unroll
        for (int k = 0; k < 8; ++k) acc[8 + k] += wj * (float)x1[j][k];
    }
    float bv[16];
    #pragma unroll
    for (int q = 0; q < 4; ++q) {
        const float4 b4 = *(const float4*)(bias + h * 256 + li * 16 + q * 4);
        bv[q * 4 + 0] = b4.x; bv[q * 4 + 1] = b4.y;
        bv[q * 4 + 2] = b4.z; bv[q * 4 + 3] = b4.w;
    }
    half8 o0, o1;
    #pragma unroll
    for (int k = 0; k < 8; ++k) o0[k] = (_Float16)fmaxf(acc[k] * inv + bv[k], 0.f);
    #pragma unroll
    for (int k = 0; k < 8; ++k) o1[k] = (_Float16)fmaxf(acc[8 + k] * inv + bv[8 + k], 0.f);
    *(half8*)(out + (size_t)gi * OC + co) = o0;
    *(half8*)(out + (size_t)gi * OC + co + 8) = o1;
}

// ---------------------------------------------------------------------------
extern "C" void kernel_launch(void* const* d_in, const int* in_sizes, int n_in,
                              void* d_out, int out_size, void* d_ws, size_t ws_size,
                              hipStream_t stream)
{
    const float* rgb       = (const float*)d_in[0];
    const float* xm        = (const float*)d_in[1];
    const float* fusion_w  = (const float*)d_in[3];
    const float* fusion_b  = (const float*)d_in[4];
    const float* fusion_g  = (const float*)d_in[5];
    const float* fusion_be = (const float*)d_in[6];
    const float* inproj_w  = (const float*)d_in[7];
    const float* inproj_b  = (const float*)d_in[8];
    const float* norm_g    = (const float*)d_in[9];
    const float* norm_b    = (const float*)d_in[10];
    const float* l0_wl     = (const float*)d_in[11];
    const float* l0_bl     = (const float*)d_in[12];
    const float* l0_wr     = (const float*)d_in[13];
    const float* l0_br     = (const float*)d_in[14];
    const float* l0_att    = (const float*)d_in[15];
    const float* l0_bias   = (const float*)d_in[16];
    const float* l1_wl     = (const float*)d_in[17];
    const float* l1_bl     = (const float*)d_in[18];
    const float* l1_wr     = (const float*)d_in[19];
    const float* l1_br     = (const float*)d_in[20];
    const float* l1_att    = (const float*)d_in[21];
    const float* l1_bias   = (const float*)d_in[22];
    const float* fp_w      = (const float*)d_in[23];
    const float* fp_b      = (const float*)d_in[24];

    // workspace (R7 layout)
    char* ws = (char*)d_ws;
    _Float16* Wf16 = (_Float16*)ws;                  // packed f16 weights+att
    _Float16* H1   = (_Float16*)(ws + 4194304);      //  4 MB [8192][256]
    _Float16* XLR0 = (_Float16*)(ws + 8388608);      // 32 MB [8192][2048]
    _Float16* GO0  = (_Float16*)(ws + 41943040);     // 16 MB [8192][1024]
    _Float16* XLR1 = (_Float16*)(ws + 58720256);     //  8 MB [8192][512]
    _Float16* GO1  = (_Float16*)(ws + 67108864);     //  4 MB [8192][256]

    _Float16* w_l0   = Wf16 + 327680;    // [2048][256] (wl|wr)
    _Float16* w_l1   = Wf16 + 851968;    // [512][1024] (wl|wr)
    _Float16* w_fp   = Wf16 + 1376256;   // [512][256]
    _Float16* att0_h = Wf16 + 1507328;   // [4][256] * log2e
    _Float16* att1_h = Wf16 + 1508352;   // [1][256] * log2e

    ConvTab ct;
    const float* srcs[7] = {l0_wl, l0_wr, l1_wl, l1_wr, fp_w, l0_att, l1_att};
    const int nel[7]  = {262144, 262144, 262144, 262144, 131072, 1024, 256};
    const int doff[7] = {327680, 589824, 851968, 1114112, 1376256, 1507328, 1508352};
    const int sblk[8] = {0, 128, 256, 384, 512, 576, 577, 578};
    for (int i = 0; i < 7; ++i) {
        ct.src[i] = srcs[i]; ct.nelem[i] = nel[i]; ct.dstoff[i] = doff[i];
        ct.scale[i] = (i >= 5) ? LOG2E : 1.0f;
    }
    for (int i = 0; i < 8; ++i) ct.startblk[i] = sblk[i];

    // 1: fusion + inproj (+ weight conversion) -> H1, Wf16
    fusion2b_k<<<834, 512, 0, stream>>>(
        rgb, xm, fusion_w, fusion_b, fusion_g, fusion_be,
        inproj_w, inproj_b, norm_g, norm_b, H1, Wf16, ct);

    // 2: l0 GEMM -> XLR0 (xl|xr)
    gemm3_k<4, 4, 1><<<dim3(16, 64), 256, 0, stream>>>(
        H1, w_l0, l0_bl, l0_br, 1024, XLR0, 256, 2048);

    // 3: GAT h=4 (register-resident) -> GO0
    gat4_k<4, 2048, 1024, 1024><<<2048, 256, 0, stream>>>(
        XLR0, att0_h, l0_bias, GO0);

    // 4: l1 GEMM -> XLR1
    gemm3_k<2, 4, 1><<<dim3(4, 128), 256, 0, stream>>>(
        GO0, w_l1, l1_bl, l1_br, 256, XLR1, 1024, 512);

    // 5: GAT h=1 -> GO1
    gat4_k<1, 512, 256, 256><<<512, 256, 0, stream>>>(
        XLR1, att1_h, l1_bias, GO1);

    // 6: final -> planar [2, 512, 4096] fp32
    gemm3_k<2, 4, 2><<<dim3(4, 128), 256, 0, stream>>>(
        GO1, w_fp, fp_b, fp_b, 512, d_out, 256, 512);
}

// Round 11
// 121.211 us; speedup vs baseline: 1.0499x; 1.0004x over previous
//
#include <hip/hip_runtime.h>

// ---------------------------------------------------------------------------
// SegformerGAT round 10: un-fuse R9's gatgemm (1 block/CU occupancy trap) ->
// 6 dispatches:
//  1 fusion2b : concat GEMM+LN + inproj GEMM+LN (++ weight-convert blocks)
//  2 gemm3    : l0 GEMM -> XLR0
//  3 gat4<4>  : register-resident GAT (xl of all 9 neighbors held in VGPRs,
//               single-pass, no LDS, 256-thr blocks) -> GO0
//  4 gemm3    : l1 GEMM -> XLR1
//  5 gat4<1>  : -> GO1
//  6 gemm3    : final -> planar fp32 out
// ---------------------------------------------------------------------------

#define NNODE 4096
#define LN_EPS 1e-5f
#define LOG2E 1.4426950408889634f

typedef _Float16 half8 __attribute__((ext_vector_type(8)));
typedef _Float16 half4 __attribute__((ext_vector_type(4)));
typedef _Float16 h2 __attribute__((ext_vector_type(2)));
typedef float f32x4 __attribute__((ext_vector_type(4)));

__device__ __forceinline__ float wave_reduce_sum(float v) {
    #pragma unroll
    for (int off = 32; off > 0; off >>= 1) v += __shfl_xor(v, off, 64);
    return v;
}

__device__ __forceinline__ void gload_lds16(const void* g, void* l) {
    __builtin_amdgcn_global_load_lds(
        (const __attribute__((address_space(1))) void*)g,
        (__attribute__((address_space(3))) void*)l, 16, 0, 0);
}

template<int N> __device__ __forceinline__ void waitcnt_vm() {
    if constexpr (N <= 0)      asm volatile("s_waitcnt vmcnt(0)" ::: "memory");
    else if constexpr (N == 2) asm volatile("s_waitcnt vmcnt(2)" ::: "memory");
    else if constexpr (N == 3) asm volatile("s_waitcnt vmcnt(3)" ::: "memory");
    else if constexpr (N == 4) asm volatile("s_waitcnt vmcnt(4)" ::: "memory");
    else                       asm volatile("s_waitcnt vmcnt(8)" ::: "memory");
}
__device__ __forceinline__ void lgkm0() {
    asm volatile("s_waitcnt lgkmcnt(0)" ::: "memory");
}
__device__ __forceinline__ void barrier_raw() {
    asm volatile("s_barrier" ::: "memory");
}

// ---------------------------------------------------------------------------
// 3-buffer counted-vmcnt MFMA f16 GEMM (R6/R7/R9 validated).
// OUTMODE: 1 = f16 [M,N] (swapped mfma); 2 = fp32 planar [B,N,4096].
// ---------------------------------------------------------------------------
template<int IT, int JT, int OUTMODE>
__global__ __launch_bounds__(256) void gemm3_k(
    const _Float16* __restrict__ A, const _Float16* __restrict__ W,
    const float* __restrict__ bias_lo, const float* __restrict__ bias_hi,
    int nsplit, void* __restrict__ Cout, int K, int N)
{
    constexpr int BM = 32 * IT, BN = 32 * JT;
    constexpr int CA = (BM * 4) / 256;
    constexpr int CB = (BN * 4) / 256;
    constexpr int L = CA + CB;
    __shared__ _Float16 ldsA[3][BM * 32];
    __shared__ _Float16 ldsB[3][BN * 32];

    const int tid = threadIdx.x;
    const int m0 = blockIdx.y * BM, n0 = blockIdx.x * BN;
    const int lane = tid & 63, w = tid >> 6;
    const int fr = lane & 15, kq = lane >> 4;
    const int sq = (kq ^ (fr & 3)) * 8;
    const int wm = (w & 1) * (16 * IT), wn = (w >> 1) * (16 * JT);

    const _Float16* aP[CA]; int aC[CA];
    #pragma unroll
    for (int i = 0; i < CA; ++i) {
        const int c = i * 256 + tid, r = c >> 2, q = (c & 3) ^ (r & 3);
        aP[i] = A + (size_t)(m0 + r) * K + q * 8;
        aC[i] = c * 8;
    }
    const _Float16* bP[CB]; int bC[CB];
    #pragma unroll
    for (int i = 0; i < CB; ++i) {
        const int c = i * 256 + tid, r = c >> 2, q = (c & 3) ^ (r & 3);
        bP[i] = W + (size_t)(n0 + r) * K + q * 8;
        bC[i] = c * 8;
    }

    f32x4 acc[IT][JT] = {};
    const int NT = K >> 5;

    #pragma unroll
    for (int i = 0; i < CA; ++i) gload_lds16(aP[i], &ldsA[0][aC[i]]);
    #pragma unroll
    for (int i = 0; i < CB; ++i) gload_lds16(bP[i], &ldsB[0][bC[i]]);
    #pragma unroll
    for (int i = 0; i < CA; ++i) gload_lds16(aP[i] + 32, &ldsA[1][aC[i]]);
    #pragma unroll
    for (int i = 0; i < CB; ++i) gload_lds16(bP[i] + 32, &ldsB[1][bC[i]]);

    int bi = 0;
    for (int t = 0; t < NT; ++t) {
        if (t + 1 < NT) waitcnt_vm<L>(); else waitcnt_vm<0>();
        barrier_raw();
        if (t + 2 < NT) {
            int nb = bi + 2; if (nb >= 3) nb -= 3;
            const int k2 = (t + 2) << 5;
            #pragma unroll
            for (int i = 0; i < CA; ++i) gload_lds16(aP[i] + k2, &ldsA[nb][aC[i]]);
            #pragma unroll
            for (int i = 0; i < CB; ++i) gload_lds16(bP[i] + k2, &ldsB[nb][bC[i]]);
        }
        half8 af[IT], bf[JT];
        #pragma unroll
        for (int i = 0; i < IT; ++i)
            af[i] = *(const half8*)&ldsA[bi][(wm + i * 16 + fr) * 32 + sq];
        #pragma unroll
        for (int j = 0; j < JT; ++j)
            bf[j] = *(const half8*)&ldsB[bi][(wn + j * 16 + fr) * 32 + sq];
        #pragma unroll
        for (int i = 0; i < IT; ++i)
            #pragma unroll
            for (int j = 0; j < JT; ++j) {
                if (OUTMODE == 1)
                    acc[i][j] = __builtin_amdgcn_mfma_f32_16x16x32_f16(
                        bf[j], af[i], acc[i][j], 0, 0, 0);
                else
                    acc[i][j] = __builtin_amdgcn_mfma_f32_16x16x32_f16(
                        af[i], bf[j], acc[i][j], 0, 0, 0);
            }
        ++bi; if (bi == 3) bi = 0;
    }

    if (OUTMODE == 1) {
        // swapped: lane&15 = m, regs = 4 consecutive n
        #pragma unroll
        for (int i = 0; i < IT; ++i) {
            const int m = m0 + wm + i * 16 + fr;
            #pragma unroll
            for (int j = 0; j < JT; ++j) {
                const int nb4 = n0 + wn + j * 16 + kq * 4;
                const float* bp = (nb4 < nsplit) ? bias_lo + nb4
                                                 : bias_hi + (nb4 - nsplit);
                const float4 bv = *(const float4*)bp;
                half4 ov = {(_Float16)(acc[i][j][0] + bv.x),
                            (_Float16)(acc[i][j][1] + bv.y),
                            (_Float16)(acc[i][j][2] + bv.z),
                            (_Float16)(acc[i][j][3] + bv.w)};
                *(half4*)((_Float16*)Cout + (size_t)m * N + nb4) = ov;
            }
        }
    } else {
        // planar [B, N, 4096], float4 along node (m) dim
        #pragma unroll
        for (int j = 0; j < JT; ++j) {
            const int col = n0 + wn + j * 16 + fr;
            const float bc = (col < nsplit) ? bias_lo[col] : bias_hi[col - nsplit];
            #pragma unroll
            for (int i = 0; i < IT; ++i) {
                const int mrun = m0 + wm + i * 16 + kq * 4;
                const int b = mrun >> 12, node = mrun & 4095;
                float4 ov = {acc[i][j][0] + bc, acc[i][j][1] + bc,
                             acc[i][j][2] + bc, acc[i][j][3] + bc};
                *(float4*)((float*)Cout + ((size_t)(b * N + col)) * 4096 + node) = ov;
            }
        }
    }
}

// ---------------------------------------------------------------------------
// fusion2b (R9 validated): fusion GEMM+LN then inproj GEMM+LN, fp32 weights
// reg-staged; blocks >= 256 convert late weights fp32->f16.
// ---------------------------------------------------------------------------
struct ConvTab {
    const float* src[7];
    int startblk[8];
    int nelem[7];
    int dstoff[7];
    float scale[7];
};

__global__ __launch_bounds__(512) void fusion2b_k(
    const float* __restrict__ A0, const float* __restrict__ A1,
    const float* __restrict__ W1f, const float* __restrict__ b1,
    const float* __restrict__ g1, const float* __restrict__ be1,
    const float* __restrict__ W2f, const float* __restrict__ b2,
    const float* __restrict__ g2, const float* __restrict__ be2,
    _Float16* __restrict__ out, _Float16* __restrict__ wdst, ConvTab ct)
{
    if (blockIdx.x >= 256) {            // weight-conversion role
        const int cid = blockIdx.x - 256;
        int s = 0;
        #pragma unroll
        for (int i = 1; i < 7; ++i) s += (cid >= ct.startblk[i]);
        const int e0 = (cid - ct.startblk[s]) * 2048 + threadIdx.x * 4;
        if (e0 < ct.nelem[s]) {
            const float4 v = *(const float4*)(ct.src[s] + e0);
            const float sc = ct.scale[s];
            half4 o = {(_Float16)(v.x * sc), (_Float16)(v.y * sc),
                       (_Float16)(v.z * sc), (_Float16)(v.w * sc)};
            *(half4*)(wdst + ct.dstoff[s] + e0) = o;
        }
        return;
    }

    __shared__ _Float16 lA[2][32 * 32];
    __shared__ _Float16 lB[2][256 * 32];
    __shared__ float lC[32 * 260];
    __shared__ _Float16 lH[8 * 1024];

    const int tid = threadIdx.x;
    const int m0 = blockIdx.x * 32;
    const int lane = tid & 63, w = tid >> 6;
    const int fr = lane & 15, kq = lane >> 4;
    const int sq = (kq ^ (fr & 3)) * 8;
    const int wr = (w & 1) * 16, wc = (w >> 1) * 64;
    const bool stager = (tid < 128);

    const int br_ = tid >> 3, bf_ = tid & 7;
    const int bq_ = bf_ >> 1, bo_ = bf_ & 1;
    float4 pb[4];

    const int ar = tid >> 2, aq = tid & 3;
    const int asw = (ar * 4 + (aq ^ (ar & 3))) * 8;
    float4 pa0, pa1;

    auto loadB = [&](const float* Wf, int ldw, int k0) {
        #pragma unroll
        for (int i = 0; i < 4; ++i)
            pb[i] = *(const float4*)(Wf + (size_t)(br_ + i * 64) * ldw + k0 + bf_ * 4);
    };
    auto writeB = [&](int buf) {
        #pragma unroll
        for (int i = 0; i < 4; ++i) {
            const int r = br_ + i * 64;
            half4 o = {(_Float16)pb[i].x, (_Float16)pb[i].y,
                       (_Float16)pb[i].z, (_Float16)pb[i].w};
            *(half4*)&lB[buf][(r * 4 + (bq_ ^ (r & 3))) * 8 + bo_ * 4] = o;
        }
    };
    auto loadA = [&](int k) {
        const int gk = k + aq * 8;
        const float* s = (gk < 512) ? A0 + (size_t)(m0 + ar) * 512 + gk
                                    : A1 + (size_t)(m0 + ar) * 512 + gk - 512;
        pa0 = *(const float4*)s;
        pa1 = *(const float4*)(s + 4);
    };
    auto writeA = [&](int buf) {
        half8 hv = {(_Float16)pa0.x, (_Float16)pa0.y, (_Float16)pa0.z, (_Float16)pa0.w,
                    (_Float16)pa1.x, (_Float16)pa1.y, (_Float16)pa1.z, (_Float16)pa1.w};
        *(half8*)&lA[buf][asw] = hv;
    };

    // ---- phase 1: K=1024, NT=32 ----
    f32x4 acc1[4] = {};
    if (stager) { loadA(0); writeA(0); loadA(32); }
    loadB(W1f, 1024, 0); writeB(0); loadB(W1f, 1024, 32);
    lgkm0(); barrier_raw();
    for (int t = 0; t < 32; ++t) {
        if (t + 1 < 32) { writeB((t + 1) & 1); if (stager) writeA((t + 1) & 1); }
        lgkm0(); barrier_raw();
        if (t + 2 < 32) { loadB(W1f, 1024, (t + 2) * 32); if (stager) loadA((t + 2) * 32); }
        const half8 af = *(const half8*)&lA[t & 1][(wr + fr) * 32 + sq];
        half8 bfr[4];
        #pragma unroll
        for (int j = 0; j < 4; ++j)
            bfr[j] = *(const half8*)&lB[t & 1][(wc + j * 16 + fr) * 32 + sq];
        #pragma unroll
        for (int j = 0; j < 4; ++j)
            acc1[j] = __builtin_amdgcn_mfma_f32_16x16x32_f16(af, bfr[j], acc1[j], 0, 0, 0);
        lgkm0(); barrier_raw();
    }

    #pragma unroll
    for (int j = 0; j < 4; ++j) {
        const int col = wc + j * 16 + fr;
        const float bc = b1[col];
        #pragma unroll
        for (int r4 = 0; r4 < 4; ++r4)
            lC[(wr + kq * 4 + r4) * 260 + col] = acc1[j][r4] + bc;
    }
    __syncthreads();

    {   // LN1 + ReLU -> lH
        const float4 gv = *(const float4*)(g1 + lane * 4);
        const float4 bv = *(const float4*)(be1 + lane * 4);
        const int t2i = lane >> 3, gq = (lane >> 1) & 3, qo = (lane & 1) * 4;
        #pragma unroll
        for (int rr = 0; rr < 4; ++rr) {
            const int row = w * 4 + rr;
            const float4 v = *(const float4*)&lC[row * 260 + lane * 4];
            float s  = v.x + v.y + v.z + v.w;
            float s2 = v.x * v.x + v.y * v.y + v.z * v.z + v.w * v.w;
            s = wave_reduce_sum(s);
            s2 = wave_reduce_sum(s2);
            const float mu  = s * (1.0f / 256.0f);
            const float var = s2 * (1.0f / 256.0f) - mu * mu;
            const float rs  = rsqrtf(var + LN_EPS);
            half4 o;
            o[0] = (_Float16)fmaxf((v.x - mu) * rs * gv.x + bv.x, 0.f);
            o[1] = (_Float16)fmaxf((v.y - mu) * rs * gv.y + bv.y, 0.f);
            o[2] = (_Float16)fmaxf((v.z - mu) * rs * gv.z + bv.z, 0.f);
            o[3] = (_Float16)fmaxf((v.w - mu) * rs * gv.w + bv.w, 0.f);
            const int qslot = gq ^ (row & 3);
            *(half4*)&lH[t2i * 1024 + (row * 4 + qslot) * 8 + qo] = o;
        }
    }
    __syncthreads();

    // ---- phase 2: K=256, NT=8, A from lH ----
    f32x4 acc2[4] = {};
    loadB(W2f, 256, 0); writeB(0); loadB(W2f, 256, 32);
    lgkm0(); barrier_raw();
    for (int t = 0; t < 8; ++t) {
        if (t + 1 < 8) writeB((t + 1) & 1);
        lgkm0(); barrier_raw();
        if (t + 2 < 8) loadB(W2f, 256, (t + 2) * 32);
        const half8 af = *(const half8*)
            &lH[t * 1024 + ((wr + fr) * 4 + (kq ^ (fr & 3))) * 8];
        half8 bfr[4];
        #pragma unroll
        for (int j = 0; j < 4; ++j)
            bfr[j] = *(const half8*)&lB[t & 1][(wc + j * 16 + fr) * 32 + sq];
        #pragma unroll
        for (int j = 0; j < 4; ++j)
            acc2[j] = __builtin_amdgcn_mfma_f32_16x16x32_f16(af, bfr[j], acc2[j], 0, 0, 0);
        lgkm0(); barrier_raw();
    }

    #pragma unroll
    for (int j = 0; j < 4; ++j) {
        const int col = wc + j * 16 + fr;
        const float bc = b2[col];
        #pragma unroll
        for (int r4 = 0; r4 < 4; ++r4)
            lC[(wr + kq * 4 + r4) * 260 + col] = acc2[j][r4] + bc;
    }
    __syncthreads();

    {   // LN2 + ReLU -> out
        const float4 gv = *(const float4*)(g2 + lane * 4);
        const float4 bv = *(const float4*)(be2 + lane * 4);
        #pragma unroll
        for (int rr = 0; rr < 4; ++rr) {
            const int row = w * 4 + rr;
            const float4 v = *(const float4*)&lC[row * 260 + lane * 4];
            float s  = v.x + v.y + v.z + v.w;
            float s2 = v.x * v.x + v.y * v.y + v.z * v.z + v.w * v.w;
            s = wave_reduce_sum(s);
            s2 = wave_reduce_sum(s2);
            const float mu  = s * (1.0f / 256.0f);
            const float var = s2 * (1.0f / 256.0f) - mu * mu;
            const float rs  = rsqrtf(var + LN_EPS);
            half4 o;
            o[0] = (_Float16)fmaxf((v.x - mu) * rs * gv.x + bv.x, 0.f);
            o[1] = (_Float16)fmaxf((v.y - mu) * rs * gv.y + bv.y, 0.f);
            o[2] = (_Float16)fmaxf((v.z - mu) * rs * gv.z + bv.z, 0.f);
            o[3] = (_Float16)fmaxf((v.w - mu) * rs * gv.w + bv.w, 0.f);
            *(half4*)(out + (size_t)(m0 + row) * 256 + lane * 4) = o;
        }
    }
}

// ---------------------------------------------------------------------------
// gat4: register-resident GAT, no LDS, 256-thr blocks, single xl pass.
// Wave = 4 groups of 16 lanes. HEADS=4: wave = 1 row, groups = heads.
// HEADS=1: wave = 4 rows. All 9 neighbor xl slices + xr loaded once into
// VGPRs; logits (4-stage group shfl), softmax (log2-domain att), weighted
// sum, +bias +ReLU, store.
// ---------------------------------------------------------------------------
template<int HEADS, int LD, int XROFF, int OC>
__global__ __launch_bounds__(256) void gat4_k(
    const _Float16* __restrict__ xlr, const _Float16* __restrict__ att16,
    const float* __restrict__ bias, _Float16* __restrict__ out)
{
    const int tid = threadIdx.x, wv = tid >> 6, lane = tid & 63;
    const int g = lane >> 4, li = lane & 15;
    const int wid = blockIdx.x * 4 + wv;
    const int gi = (HEADS == 4) ? wid : wid * 4 + g;
    const int h  = (HEADS == 4) ? g : 0;
    const int node = gi & (NNODE - 1);
    const int base = gi - node;
    const int nr = node >> 6, nc = node & 63;
    const int co = h * 256 + li * 16;

    int sidx[9]; float msk[9];
    {
        const int drs[8] = {-1,-1,-1, 0, 0, 1, 1, 1};
        const int dcs[8] = {-1, 0, 1,-1, 1,-1, 0, 1};
        #pragma unroll
        for (int j = 0; j < 8; ++j) {
            const int rj = nr + drs[j], cj = nc + dcs[j];
            const bool v = ((unsigned)rj < 64u) & ((unsigned)cj < 64u);
            sidx[j] = v ? (rj * 64 + cj) : node;
            msk[j] = v ? 0.f : -1e30f;
        }
        sidx[8] = node; msk[8] = 0.f;
    }

    const _Float16* xp = xlr + (size_t)base * LD + co;

    // load ALL xl slices + xr + att up front (independent loads, one wait)
    half8 x0[9], x1[9];
    #pragma unroll
    for (int j = 0; j < 9; ++j) {
        x0[j] = *(const half8*)(xp + (size_t)sidx[j] * LD);
        x1[j] = *(const half8*)(xp + (size_t)sidx[j] * LD + 8);
    }
    const half8 xr0 = *(const half8*)(xlr + (size_t)gi * LD + XROFF + co);
    const half8 xr1 = *(const half8*)(xlr + (size_t)gi * LD + XROFF + co + 8);
    const half8 at0 = *(const half8*)(att16 + h * 256 + li * 16);
    const half8 at1 = *(const half8*)(att16 + h * 256 + li * 16 + 8);
    const h2 hz = {(_Float16)0.f, (_Float16)0.f};
    const h2 c02 = {(_Float16)0.2f, (_Float16)0.2f};

    float lg[9];
    #pragma unroll
    for (int j = 0; j < 9; ++j) {
        h2 p = hz;
        #pragma unroll
        for (int k = 0; k < 4; ++k) {
            h2 e = ((const h2*)&x0[j])[k] + ((const h2*)&xr0)[k];
            h2 tt = __builtin_elementwise_fma(
                __builtin_elementwise_min(e, hz), c02,
                __builtin_elementwise_max(e, hz));
            p = __builtin_elementwise_fma(tt, ((const h2*)&at0)[k], p);
        }
        #pragma unroll
        for (int k = 0; k < 4; ++k) {
            h2 e = ((const h2*)&x1[j])[k] + ((const h2*)&xr1)[k];
            h2 tt = __builtin_elementwise_fma(
                __builtin_elementwise_min(e, hz), c02,
                __builtin_elementwise_max(e, hz));
            p = __builtin_elementwise_fma(tt, ((const h2*)&at1)[k], p);
        }
        float pl = (float)p[0] + (float)p[1];
        pl += __shfl_xor(pl, 1, 64);
        pl += __shfl_xor(pl, 2, 64);
        pl += __shfl_xor(pl, 4, 64);
        pl += __shfl_xor(pl, 8, 64);
        lg[j] = pl + msk[j];                 // log2-domain logits
    }

    float m = lg[0];
    #pragma unroll
    for (int j = 1; j < 9; ++j) m = fmaxf(m, lg[j]);
    float pj[9], z = 0.f;
    #pragma unroll
    for (int j = 0; j < 9; ++j) { pj[j] = __builtin_amdgcn_exp2f(lg[j] - m); z += pj[j]; }
    const float inv = __builtin_amdgcn_rcpf(z);

    float acc[16];
    #pragma unroll
    for (int k = 0; k < 16; ++k) acc[k] = 0.f;
    #pragma unroll
    for (int j = 0; j < 9; ++j) {
        const float wj = pj[j];
        #pragma unroll
        for (int k = 0; k < 8; ++k) acc[k]     += wj * (float)x0[j][k];
        #pragma unroll
        for (int k = 0; k < 8; ++k) acc[8 + k] += wj * (float)x1[j][k];
    }
    float bv[16];
    #pragma unroll
    for (int q = 0; q < 4; ++q) {
        const float4 b4 = *(const float4*)(bias + h * 256 + li * 16 + q * 4);
        bv[q * 4 + 0] = b4.x; bv[q * 4 + 1] = b4.y;
        bv[q * 4 + 2] = b4.z; bv[q * 4 + 3] = b4.w;
    }
    half8 o0, o1;
    #pragma unroll
    for (int k = 0; k < 8; ++k) o0[k] = (_Float16)fmaxf(acc[k] * inv + bv[k], 0.f);
    #pragma unroll
    for (int k = 0; k < 8; ++k) o1[k] = (_Float16)fmaxf(acc[8 + k] * inv + bv[8 + k], 0.f);
    *(half8*)(out + (size_t)gi * OC + co) = o0;
    *(half8*)(out + (size_t)gi * OC + co + 8) = o1;
}

// ---------------------------------------------------------------------------
extern "C" void kernel_launch(void* const* d_in, const int* in_sizes, int n_in,
                              void* d_out, int out_size, void* d_ws, size_t ws_size,
                              hipStream_t stream)
{
    const float* rgb       = (const float*)d_in[0];
    const float* xm        = (const float*)d_in[1];
    const float* fusion_w  = (const float*)d_in[3];
    const float* fusion_b  = (const float*)d_in[4];
    const float* fusion_g  = (const float*)d_in[5];
    const float* fusion_be = (const float*)d_in[6];
    const float* inproj_w  = (const float*)d_in[7];
    const float* inproj_b  = (const float*)d_in[8];
    const float* norm_g    = (const float*)d_in[9];
    const float* norm_b    = (const float*)d_in[10];
    const float* l0_wl     = (const float*)d_in[11];
    const float* l0_bl     = (const float*)d_in[12];
    const float* l0_wr     = (const float*)d_in[13];
    const float* l0_br     = (const float*)d_in[14];
    const float* l0_att    = (const float*)d_in[15];
    const float* l0_bias   = (const float*)d_in[16];
    const float* l1_wl     = (const float*)d_in[17];
    const float* l1_bl     = (const float*)d_in[18];
    const float* l1_wr     = (const float*)d_in[19];
    const float* l1_br     = (const float*)d_in[20];
    const float* l1_att    = (const float*)d_in[21];
    const float* l1_bias   = (const float*)d_in[22];
    const float* fp_w      = (const float*)d_in[23];
    const float* fp_b      = (const float*)d_in[24];

    // workspace (R7 layout)
    char* ws = (char*)d_ws;
    _Float16* Wf16 = (_Float16*)ws;                  // packed f16 weights+att
    _Float16* H1   = (_Float16*)(ws + 4194304);      //  4 MB [8192][256]
    _Float16* XLR0 = (_Float16*)(ws + 8388608);      // 32 MB [8192][2048]
    _Float16* GO0  = (_Float16*)(ws + 41943040);     // 16 MB [8192][1024]
    _Float16* XLR1 = (_Float16*)(ws + 58720256);     //  8 MB [8192][512]
    _Float16* GO1  = (_Float16*)(ws + 67108864);     //  4 MB [8192][256]

    _Float16* w_l0   = Wf16 + 327680;    // [2048][256] (wl|wr)
    _Float16* w_l1   = Wf16 + 851968;    // [512][1024] (wl|wr)
    _Float16* w_fp   = Wf16 + 1376256;   // [512][256]
    _Float16* att0_h = Wf16 + 1507328;   // [4][256] * log2e
    _Float16* att1_h = Wf16 + 1508352;   // [1][256] * log2e

    ConvTab ct;
    const float* srcs[7] = {l0_wl, l0_wr, l1_wl, l1_wr, fp_w, l0_att, l1_att};
    const int nel[7]  = {262144, 262144, 262144, 262144, 131072, 1024, 256};
    const int doff[7] = {327680, 589824, 851968, 1114112, 1376256, 1507328, 1508352};
    const int sblk[8] = {0, 128, 256, 384, 512, 576, 577, 578};
    for (int i = 0; i < 7; ++i) {
        ct.src[i] = srcs[i]; ct.nelem[i] = nel[i]; ct.dstoff[i] = doff[i];
        ct.scale[i] = (i >= 5) ? LOG2E : 1.0f;
    }
    for (int i = 0; i < 8; ++i) ct.startblk[i] = sblk[i];

    // 1: fusion + inproj (+ weight conversion) -> H1, Wf16
    fusion2b_k<<<834, 512, 0, stream>>>(
        rgb, xm, fusion_w, fusion_b, fusion_g, fusion_be,
        inproj_w, inproj_b, norm_g, norm_b, H1, Wf16, ct);

    // 2: l0 GEMM -> XLR0 (xl|xr)
    gemm3_k<4, 4, 1><<<dim3(16, 64), 256, 0, stream>>>(
        H1, w_l0, l0_bl, l0_br, 1024, XLR0, 256, 2048);

    // 3: GAT h=4 (register-resident) -> GO0
    gat4_k<4, 2048, 1024, 1024><<<2048, 256, 0, stream>>>(
        XLR0, att0_h, l0_bias, GO0);

    // 4: l1 GEMM -> XLR1
    gemm3_k<2, 4, 1><<<dim3(4, 128), 256, 0, stream>>>(
        GO0, w_l1, l1_bl, l1_br, 256, XLR1, 1024, 512);

    // 5: GAT h=1 -> GO1
    gat4_k<1, 512, 256, 256><<<512, 256, 0, stream>>>(
        XLR1, att1_h, l1_bias, GO1);

    // 6: final -> planar [2, 512, 4096] fp32
    gemm3_k<2, 4, 2><<<dim3(4, 128), 256, 0, stream>>>(
        GO1, w_fp, fp_b, fp_b, 512, d_out, 256, 512);
}

// Round 12
// 120.641 us; speedup vs baseline: 1.0548x; 1.0047x over previous
//
#include <hip/hip_runtime.h>

// ---------------------------------------------------------------------------
// SegformerGAT round 12: revert fusion to R7's validated fast path.
//  1 wconv    : all weights fp32->f16 packed (att * log2e)
//  2 fusion2  : concat GEMM(K=1024)+LN + inproj GEMM(K=256)+LN (f16 weights
//               via global_load_lds, counted-vmcnt 3-buffer; R7 validated)
//  3 gemm3    : l0 GEMM -> XLR0
//  4 gat4<4>  : register-resident GAT (R11 validated) -> GO0
//  5 gemm3    : l1 GEMM -> XLR1
//  6 gat4<1>  : -> GO1
//  7 gemm3    : final -> planar fp32 out
// ---------------------------------------------------------------------------

#define NNODE 4096
#define LN_EPS 1e-5f
#define LOG2E 1.4426950408889634f

typedef _Float16 half8 __attribute__((ext_vector_type(8)));
typedef _Float16 half4 __attribute__((ext_vector_type(4)));
typedef _Float16 h2 __attribute__((ext_vector_type(2)));
typedef float f32x4 __attribute__((ext_vector_type(4)));

__device__ __forceinline__ float wave_reduce_sum(float v) {
    #pragma unroll
    for (int off = 32; off > 0; off >>= 1) v += __shfl_xor(v, off, 64);
    return v;
}

__device__ __forceinline__ void gload_lds16(const void* g, void* l) {
    __builtin_amdgcn_global_load_lds(
        (const __attribute__((address_space(1))) void*)g,
        (__attribute__((address_space(3))) void*)l, 16, 0, 0);
}

template<int N> __device__ __forceinline__ void waitcnt_vm() {
    if constexpr (N <= 0)      asm volatile("s_waitcnt vmcnt(0)" ::: "memory");
    else if constexpr (N == 2) asm volatile("s_waitcnt vmcnt(2)" ::: "memory");
    else if constexpr (N == 3) asm volatile("s_waitcnt vmcnt(3)" ::: "memory");
    else if constexpr (N == 4) asm volatile("s_waitcnt vmcnt(4)" ::: "memory");
    else                       asm volatile("s_waitcnt vmcnt(8)" ::: "memory");
}
template<int N> __device__ __forceinline__ void waitcnt_vm_lgkm() {
    if constexpr (N <= 0)      asm volatile("s_waitcnt vmcnt(0) lgkmcnt(0)" ::: "memory");
    else if constexpr (N == 2) asm volatile("s_waitcnt vmcnt(2) lgkmcnt(0)" ::: "memory");
    else if constexpr (N == 3) asm volatile("s_waitcnt vmcnt(3) lgkmcnt(0)" ::: "memory");
    else                       asm volatile("s_waitcnt vmcnt(4) lgkmcnt(0)" ::: "memory");
}
__device__ __forceinline__ void barrier_raw() {
    asm volatile("s_barrier" ::: "memory");
}

// ---------------------------------------------------------------------------
// 3-buffer counted-vmcnt MFMA f16 GEMM (R6/R7/R11 validated).
// OUTMODE: 1 = f16 [M,N] (swapped mfma); 2 = fp32 planar [B,N,4096].
// ---------------------------------------------------------------------------
template<int IT, int JT, int OUTMODE>
__global__ __launch_bounds__(256) void gemm3_k(
    const _Float16* __restrict__ A, const _Float16* __restrict__ W,
    const float* __restrict__ bias_lo, const float* __restrict__ bias_hi,
    int nsplit, void* __restrict__ Cout, int K, int N)
{
    constexpr int BM = 32 * IT, BN = 32 * JT;
    constexpr int CA = (BM * 4) / 256;
    constexpr int CB = (BN * 4) / 256;
    constexpr int L = CA + CB;
    __shared__ _Float16 ldsA[3][BM * 32];
    __shared__ _Float16 ldsB[3][BN * 32];

    const int tid = threadIdx.x;
    const int m0 = blockIdx.y * BM, n0 = blockIdx.x * BN;
    const int lane = tid & 63, w = tid >> 6;
    const int fr = lane & 15, kq = lane >> 4;
    const int sq = (kq ^ (fr & 3)) * 8;
    const int wm = (w & 1) * (16 * IT), wn = (w >> 1) * (16 * JT);

    const _Float16* aP[CA]; int aC[CA];
    #pragma unroll
    for (int i = 0; i < CA; ++i) {
        const int c = i * 256 + tid, r = c >> 2, q = (c & 3) ^ (r & 3);
        aP[i] = A + (size_t)(m0 + r) * K + q * 8;
        aC[i] = c * 8;
    }
    const _Float16* bP[CB]; int bC[CB];
    #pragma unroll
    for (int i = 0; i < CB; ++i) {
        const int c = i * 256 + tid, r = c >> 2, q = (c & 3) ^ (r & 3);
        bP[i] = W + (size_t)(n0 + r) * K + q * 8;
        bC[i] = c * 8;
    }

    f32x4 acc[IT][JT] = {};
    const int NT = K >> 5;

    #pragma unroll
    for (int i = 0; i < CA; ++i) gload_lds16(aP[i], &ldsA[0][aC[i]]);
    #pragma unroll
    for (int i = 0; i < CB; ++i) gload_lds16(bP[i], &ldsB[0][bC[i]]);
    #pragma unroll
    for (int i = 0; i < CA; ++i) gload_lds16(aP[i] + 32, &ldsA[1][aC[i]]);
    #pragma unroll
    for (int i = 0; i < CB; ++i) gload_lds16(bP[i] + 32, &ldsB[1][bC[i]]);

    int bi = 0;
    for (int t = 0; t < NT; ++t) {
        if (t + 1 < NT) waitcnt_vm<L>(); else waitcnt_vm<0>();
        barrier_raw();
        if (t + 2 < NT) {
            int nb = bi + 2; if (nb >= 3) nb -= 3;
            const int k2 = (t + 2) << 5;
            #pragma unroll
            for (int i = 0; i < CA; ++i) gload_lds16(aP[i] + k2, &ldsA[nb][aC[i]]);
            #pragma unroll
            for (int i = 0; i < CB; ++i) gload_lds16(bP[i] + k2, &ldsB[nb][bC[i]]);
        }
        half8 af[IT], bf[JT];
        #pragma unroll
        for (int i = 0; i < IT; ++i)
            af[i] = *(const half8*)&ldsA[bi][(wm + i * 16 + fr) * 32 + sq];
        #pragma unroll
        for (int j = 0; j < JT; ++j)
            bf[j] = *(const half8*)&ldsB[bi][(wn + j * 16 + fr) * 32 + sq];
        #pragma unroll
        for (int i = 0; i < IT; ++i)
            #pragma unroll
            for (int j = 0; j < JT; ++j) {
                if (OUTMODE == 1)
                    acc[i][j] = __builtin_amdgcn_mfma_f32_16x16x32_f16(
                        bf[j], af[i], acc[i][j], 0, 0, 0);
                else
                    acc[i][j] = __builtin_amdgcn_mfma_f32_16x16x32_f16(
                        af[i], bf[j], acc[i][j], 0, 0, 0);
            }
        ++bi; if (bi == 3) bi = 0;
    }

    if (OUTMODE == 1) {
        // swapped: lane&15 = m, regs = 4 consecutive n
        #pragma unroll
        for (int i = 0; i < IT; ++i) {
            const int m = m0 + wm + i * 16 + fr;
            #pragma unroll
            for (int j = 0; j < JT; ++j) {
                const int nb4 = n0 + wn + j * 16 + kq * 4;
                const float* bp = (nb4 < nsplit) ? bias_lo + nb4
                                                 : bias_hi + (nb4 - nsplit);
                const float4 bv = *(const float4*)bp;
                half4 ov = {(_Float16)(acc[i][j][0] + bv.x),
                            (_Float16)(acc[i][j][1] + bv.y),
                            (_Float16)(acc[i][j][2] + bv.z),
                            (_Float16)(acc[i][j][3] + bv.w)};
                *(half4*)((_Float16*)Cout + (size_t)m * N + nb4) = ov;
            }
        }
    } else {
        // planar [B, N, 4096], float4 along node (m) dim
        #pragma unroll
        for (int j = 0; j < JT; ++j) {
            const int col = n0 + wn + j * 16 + fr;
            const float bc = (col < nsplit) ? bias_lo[col] : bias_hi[col - nsplit];
            #pragma unroll
            for (int i = 0; i < IT; ++i) {
                const int mrun = m0 + wm + i * 16 + kq * 4;
                const int b = mrun >> 12, node = mrun & 4095;
                float4 ov = {acc[i][j][0] + bc, acc[i][j][1] + bc,
                             acc[i][j][2] + bc, acc[i][j][3] + bc};
                *(float4*)((float*)Cout + ((size_t)(b * N + col)) * 4096 + node) = ov;
            }
        }
    }
}

// ---------------------------------------------------------------------------
// fusion2 (R7 validated): [concat(rgb,xm) @ W1^T + b1 -> LN -> ReLU] in LDS,
// then [@ W2^T + b2 -> LN -> ReLU] -> out f16. BM=32, BN=256, 8 waves,
// 3-buffer counted-vmcnt pipelines; W1/W2 are pre-converted f16.
// ---------------------------------------------------------------------------
__global__ __launch_bounds__(512) void fusion2_k(
    const float* __restrict__ A0, const float* __restrict__ A1,
    const _Float16* __restrict__ W1, const float* __restrict__ b1,
    const float* __restrict__ g1, const float* __restrict__ be1,
    const _Float16* __restrict__ W2, const float* __restrict__ b2,
    const float* __restrict__ g2, const float* __restrict__ be2,
    _Float16* __restrict__ out)
{
    __shared__ _Float16 lA[3][32 * 32];
    __shared__ _Float16 lB[3][256 * 32];
    __shared__ float lC[32 * 260];
    __shared__ _Float16 lH[8 * 1024];          // [t2][row*4+qslot][8]

    const int tid = threadIdx.x;               // 0..511
    const int m0 = blockIdx.x * 32;
    const int lane = tid & 63, w = tid >> 6;
    const int fr = lane & 15, kq = lane >> 4;
    const int sq = (kq ^ (fr & 3)) * 8;
    const int wr = (w & 1) * 16, wc = (w >> 1) * 64;
    const bool stager = (tid < 128);

    // phase-1 B staging (W1, K=1024): pre-swizzled source, linear gload dest
    const _Float16* bP[2]; int bC[2];
    #pragma unroll
    for (int i = 0; i < 2; ++i) {
        const int c = i * 512 + tid, r = c >> 2, q = (c & 3) ^ (r & 3);
        bP[i] = W1 + (size_t)r * 1024 + q * 8;
        bC[i] = c * 8;
    }
    // A staging (concat fp32, reg-staged; natural source quad, swizzled dest)
    const int ar = tid >> 2, aq = tid & 3;
    const int asw = (ar * 4 + (aq ^ (ar & 3))) * 8;
    float4 p0, p1;
    auto loadA = [&](int k) {
        const int gk = k + aq * 8;
        const float* s = (gk < 512) ? A0 + (size_t)(m0 + ar) * 512 + gk
                                    : A1 + (size_t)(m0 + ar) * 512 + gk - 512;
        p0 = *(const float4*)s;
        p1 = *(const float4*)(s + 4);
    };
    auto writeA = [&](int b) {
        half8 hv = {(_Float16)p0.x, (_Float16)p0.y, (_Float16)p0.z, (_Float16)p0.w,
                    (_Float16)p1.x, (_Float16)p1.y, (_Float16)p1.z, (_Float16)p1.w};
        *(half8*)&lA[b][asw] = hv;
    };

    f32x4 acc[4] = {};

    // ---- phase 1: K=1024, NT=32 ----
    if (stager) { loadA(0); writeA(0); loadA(32); }
    #pragma unroll
    for (int i = 0; i < 2; ++i) gload_lds16(bP[i], &lB[0][bC[i]]);
    #pragma unroll
    for (int i = 0; i < 2; ++i) gload_lds16(bP[i] + 32, &lB[1][bC[i]]);

    int bi = 0;
    for (int t = 0; t < 32; ++t) {
        if (t + 1 < 32) {
            if (stager) waitcnt_vm_lgkm<4>(); else waitcnt_vm_lgkm<2>();
        } else {
            waitcnt_vm_lgkm<0>();
        }
        barrier_raw();
        int nb1 = bi + 1; if (nb1 >= 3) nb1 -= 3;
        int nb2 = bi + 2; if (nb2 >= 3) nb2 -= 3;
        if (stager && t + 1 < 32) writeA(nb1);
        if (t + 2 < 32) {
            const int k2 = (t + 2) << 5;
            if (stager) loadA(k2);
            #pragma unroll
            for (int i = 0; i < 2; ++i) gload_lds16(bP[i] + k2, &lB[nb2][bC[i]]);
        }
        half8 af = *(const half8*)&lA[bi][(wr + fr) * 32 + sq];
        half8 bf[4];
        #pragma unroll
        for (int j = 0; j < 4; ++j)
            bf[j] = *(const half8*)&lB[bi][(wc + j * 16 + fr) * 32 + sq];
        #pragma unroll
        for (int j = 0; j < 4; ++j)
            acc[j] = __builtin_amdgcn_mfma_f32_16x16x32_f16(af, bf[j], acc[j], 0, 0, 0);
        ++bi; if (bi == 3) bi = 0;
    }

    // C1 -> lC (fp32 + b1)
    #pragma unroll
    for (int j = 0; j < 4; ++j) {
        const int col = wc + j * 16 + fr;
        const float bc = b1[col];
        #pragma unroll
        for (int r4 = 0; r4 < 4; ++r4)
            lC[(wr + kq * 4 + r4) * 260 + col] = acc[j][r4] + bc;
    }
    __syncthreads();

    // LN1 + ReLU -> lH (f16, gload-compatible swizzled tiles)
    {
        const float4 gv = *(const float4*)(g1 + lane * 4);
        const float4 bv = *(const float4*)(be1 + lane * 4);
        const int t2i = lane >> 3, gq = (lane >> 1) & 3, qo = (lane & 1) * 4;
        #pragma unroll
        for (int rr = 0; rr < 4; ++rr) {
            const int row = w * 4 + rr;
            const float4 v = *(const float4*)&lC[row * 260 + lane * 4];
            float s  = v.x + v.y + v.z + v.w;
            float s2 = v.x * v.x + v.y * v.y + v.z * v.z + v.w * v.w;
            s = wave_reduce_sum(s);
            s2 = wave_reduce_sum(s2);
            const float mu  = s * (1.0f / 256.0f);
            const float var = s2 * (1.0f / 256.0f) - mu * mu;
            const float rs  = rsqrtf(var + LN_EPS);
            half4 o;
            o[0] = (_Float16)fmaxf((v.x - mu) * rs * gv.x + bv.x, 0.f);
            o[1] = (_Float16)fmaxf((v.y - mu) * rs * gv.y + bv.y, 0.f);
            o[2] = (_Float16)fmaxf((v.z - mu) * rs * gv.z + bv.z, 0.f);
            o[3] = (_Float16)fmaxf((v.w - mu) * rs * gv.w + bv.w, 0.f);
            const int qslot = gq ^ (row & 3);
            *(half4*)&lH[t2i * 1024 + (row * 4 + qslot) * 8 + qo] = o;
        }
    }
    __syncthreads();

    // ---- phase 2: K=256, NT=8, A from lH ----
    const _Float16* b2P[2]; int b2C[2];
    #pragma unroll
    for (int i = 0; i < 2; ++i) {
        const int c = i * 512 + tid, r = c >> 2, q = (c & 3) ^ (r & 3);
        b2P[i] = W2 + (size_t)r * 256 + q * 8;
        b2C[i] = c * 8;
    }
    f32x4 acc2[4] = {};
    #pragma unroll
    for (int i = 0; i < 2; ++i) gload_lds16(b2P[i], &lB[0][b2C[i]]);
    #pragma unroll
    for (int i = 0; i < 2; ++i) gload_lds16(b2P[i] + 32, &lB[1][b2C[i]]);

    int bi2 = 0;
    for (int t2 = 0; t2 < 8; ++t2) {
        if (t2 + 1 < 8) waitcnt_vm<2>(); else waitcnt_vm<0>();
        barrier_raw();
        if (t2 + 2 < 8) {
            int nb = bi2 + 2; if (nb >= 3) nb -= 3;
            const int k2 = (t2 + 2) << 5;
            #pragma unroll
            for (int i = 0; i < 2; ++i) gload_lds16(b2P[i] + k2, &lB[nb][b2C[i]]);
        }
        const half8 af = *(const half8*)
            &lH[t2 * 1024 + ((wr + fr) * 4 + (kq ^ (fr & 3))) * 8];
        half8 bf[4];
        #pragma unroll
        for (int j = 0; j < 4; ++j)
            bf[j] = *(const half8*)&lB[bi2][(wc + j * 16 + fr) * 32 + sq];
        #pragma unroll
        for (int j = 0; j < 4; ++j)
            acc2[j] = __builtin_amdgcn_mfma_f32_16x16x32_f16(af, bf[j], acc2[j], 0, 0, 0);
        ++bi2; if (bi2 == 3) bi2 = 0;
    }

    // C2 -> lC (fp32 + b2)
    #pragma unroll
    for (int j = 0; j < 4; ++j) {
        const int col = wc + j * 16 + fr;
        const float bc = b2[col];
        #pragma unroll
        for (int r4 = 0; r4 < 4; ++r4)
            lC[(wr + kq * 4 + r4) * 260 + col] = acc2[j][r4] + bc;
    }
    __syncthreads();

    // LN2 + ReLU -> out (global f16)
    {
        const float4 gv = *(const float4*)(g2 + lane * 4);
        const float4 bv = *(const float4*)(be2 + lane * 4);
        #pragma unroll
        for (int rr = 0; rr < 4; ++rr) {
            const int row = w * 4 + rr;
            const float4 v = *(const float4*)&lC[row * 260 + lane * 4];
            float s  = v.x + v.y + v.z + v.w;
            float s2 = v.x * v.x + v.y * v.y + v.z * v.z + v.w * v.w;
            s = wave_reduce_sum(s);
            s2 = wave_reduce_sum(s2);
            const float mu  = s * (1.0f / 256.0f);
            const float var = s2 * (1.0f / 256.0f) - mu * mu;
            const float rs  = rsqrtf(var + LN_EPS);
            half4 o;
            o[0] = (_Float16)fmaxf((v.x - mu) * rs * gv.x + bv.x, 0.f);
            o[1] = (_Float16)fmaxf((v.y - mu) * rs * gv.y + bv.y, 0.f);
            o[2] = (_Float16)fmaxf((v.z - mu) * rs * gv.z + bv.z, 0.f);
            o[3] = (_Float16)fmaxf((v.w - mu) * rs * gv.w + bv.w, 0.f);
            *(half4*)(out + (size_t)(m0 + row) * 256 + lane * 4) = o;
        }
    }
}

// ---------------------------------------------------------------------------
// gat4 (R11 validated): register-resident GAT, no LDS, 256-thr blocks.
// ---------------------------------------------------------------------------
template<int HEADS, int LD, int XROFF, int OC>
__global__ __launch_bounds__(256) void gat4_k(
    const _Float16* __restrict__ xlr, const _Float16* __restrict__ att16,
    const float* __restrict__ bias, _Float16* __restrict__ out)
{
    const int tid = threadIdx.x, wv = tid >> 6, lane = tid & 63;
    const int g = lane >> 4, li = lane & 15;
    const int wid = blockIdx.x * 4 + wv;
    const int gi = (HEADS == 4) ? wid : wid * 4 + g;
    const int h  = (HEADS == 4) ? g : 0;
    const int node = gi & (NNODE - 1);
    const int base = gi - node;
    const int nr = node >> 6, nc = node & 63;
    const int co = h * 256 + li * 16;

    int sidx[9]; float msk[9];
    {
        const int drs[8] = {-1,-1,-1, 0, 0, 1, 1, 1};
        const int dcs[8] = {-1, 0, 1,-1, 1,-1, 0, 1};
        #pragma unroll
        for (int j = 0; j < 8; ++j) {
            const int rj = nr + drs[j], cj = nc + dcs[j];
            const bool v = ((unsigned)rj < 64u) & ((unsigned)cj < 64u);
            sidx[j] = v ? (rj * 64 + cj) : node;
            msk[j] = v ? 0.f : -1e30f;
        }
        sidx[8] = node; msk[8] = 0.f;
    }

    const _Float16* xp = xlr + (size_t)base * LD + co;

    half8 x0[9], x1[9];
    #pragma unroll
    for (int j = 0; j < 9; ++j) {
        x0[j] = *(const half8*)(xp + (size_t)sidx[j] * LD);
        x1[j] = *(const half8*)(xp + (size_t)sidx[j] * LD + 8);
    }
    const half8 xr0 = *(const half8*)(xlr + (size_t)gi * LD + XROFF + co);
    const half8 xr1 = *(const half8*)(xlr + (size_t)gi * LD + XROFF + co + 8);
    const half8 at0 = *(const half8*)(att16 + h * 256 + li * 16);
    const half8 at1 = *(const half8*)(att16 + h * 256 + li * 16 + 8);
    const h2 hz = {(_Float16)0.f, (_Float16)0.f};
    const h2 c02 = {(_Float16)0.2f, (_Float16)0.2f};

    float lg[9];
    #pragma unroll
    for (int j = 0; j < 9; ++j) {
        h2 p = hz;
        #pragma unroll
        for (int k = 0; k < 4; ++k) {
            h2 e = ((const h2*)&x0[j])[k] + ((const h2*)&xr0)[k];
            h2 tt = __builtin_elementwise_fma(
                __builtin_elementwise_min(e, hz), c02,
                __builtin_elementwise_max(e, hz));
            p = __builtin_elementwise_fma(tt, ((const h2*)&at0)[k], p);
        }
        #pragma unroll
        for (int k = 0; k < 4; ++k) {
            h2 e = ((const h2*)&x1[j])[k] + ((const h2*)&xr1)[k];
            h2 tt = __builtin_elementwise_fma(
                __builtin_elementwise_min(e, hz), c02,
                __builtin_elementwise_max(e, hz));
            p = __builtin_elementwise_fma(tt, ((const h2*)&at1)[k], p);
        }
        float pl = (float)p[0] + (float)p[1];
        pl += __shfl_xor(pl, 1, 64);
        pl += __shfl_xor(pl, 2, 64);
        pl += __shfl_xor(pl, 4, 64);
        pl += __shfl_xor(pl, 8, 64);
        lg[j] = pl + msk[j];                 // log2-domain logits
    }

    float m = lg[0];
    #pragma unroll
    for (int j = 1; j < 9; ++j) m = fmaxf(m, lg[j]);
    float pj[9], z = 0.f;
    #pragma unroll
    for (int j = 0; j < 9; ++j) { pj[j] = __builtin_amdgcn_exp2f(lg[j] - m); z += pj[j]; }
    const float inv = __builtin_amdgcn_rcpf(z);

    float acc[16];
    #pragma unroll
    for (int k = 0; k < 16; ++k) acc[k] = 0.f;
    #pragma unroll
    for (int j = 0; j < 9; ++j) {
        const float wj = pj[j];
        #pragma unroll
        for (int k = 0; k < 8; ++k) acc[k]     += wj * (float)x0[j][k];
        #pragma unroll
        for (int k = 0; k < 8; ++k) acc[8 + k] += wj * (float)x1[j][k];
    }
    float bv[16];
    #pragma unroll
    for (int q = 0; q < 4; ++q) {
        const float4 b4 = *(const float4*)(bias + h * 256 + li * 16 + q * 4);
        bv[q * 4 + 0] = b4.x; bv[q * 4 + 1] = b4.y;
        bv[q * 4 + 2] = b4.z; bv[q * 4 + 3] = b4.w;
    }
    half8 o0, o1;
    #pragma unroll
    for (int k = 0; k < 8; ++k) o0[k] = (_Float16)fmaxf(acc[k] * inv + bv[k], 0.f);
    #pragma unroll
    for (int k = 0; k < 8; ++k) o1[k] = (_Float16)fmaxf(acc[8 + k] * inv + bv[8 + k], 0.f);
    *(half8*)(out + (size_t)gi * OC + co) = o0;
    *(half8*)(out + (size_t)gi * OC + co + 8) = o1;
}

// ---------------------------------------------------------------------------
// Weight/att conversion fp32 -> f16 packed (R7 validated). att scaled log2e.
// ---------------------------------------------------------------------------
struct WTab {
    const float* src[9];
    int startblk[10];
    int nelem[9];
    int dstoff[9];
    float scale[9];
};

__global__ __launch_bounds__(256) void wconv_k(WTab t, _Float16* __restrict__ dst)
{
    const int b = blockIdx.x;
    int s = 0;
    #pragma unroll
    for (int i = 1; i < 9; ++i) s += (b >= t.startblk[i]);
    const int e0 = (b - t.startblk[s]) * 1024 + threadIdx.x * 4;
    if (e0 >= t.nelem[s]) return;
    const float4 v = *(const float4*)(t.src[s] + e0);
    const float sc = t.scale[s];
    half4 o = {(_Float16)(v.x * sc), (_Float16)(v.y * sc),
               (_Float16)(v.z * sc), (_Float16)(v.w * sc)};
    *(half4*)(dst + t.dstoff[s] + e0) = o;
}

// ---------------------------------------------------------------------------
extern "C" void kernel_launch(void* const* d_in, const int* in_sizes, int n_in,
                              void* d_out, int out_size, void* d_ws, size_t ws_size,
                              hipStream_t stream)
{
    const float* rgb       = (const float*)d_in[0];
    const float* xm        = (const float*)d_in[1];
    const float* fusion_w  = (const float*)d_in[3];
    const float* fusion_b  = (const float*)d_in[4];
    const float* fusion_g  = (const float*)d_in[5];
    const float* fusion_be = (const float*)d_in[6];
    const float* inproj_w  = (const float*)d_in[7];
    const float* inproj_b  = (const float*)d_in[8];
    const float* norm_g    = (const float*)d_in[9];
    const float* norm_b    = (const float*)d_in[10];
    const float* l0_wl     = (const float*)d_in[11];
    const float* l0_bl     = (const float*)d_in[12];
    const float* l0_wr     = (const float*)d_in[13];
    const float* l0_br     = (const float*)d_in[14];
    const float* l0_att    = (const float*)d_in[15];
    const float* l0_bias   = (const float*)d_in[16];
    const float* l1_wl     = (const float*)d_in[17];
    const float* l1_bl     = (const float*)d_in[18];
    const float* l1_wr     = (const float*)d_in[19];
    const float* l1_br     = (const float*)d_in[20];
    const float* l1_att    = (const float*)d_in[21];
    const float* l1_bias   = (const float*)d_in[22];
    const float* fp_w      = (const float*)d_in[23];
    const float* fp_b      = (const float*)d_in[24];

    // workspace (R7 layout)
    char* ws = (char*)d_ws;
    _Float16* Wf16 = (_Float16*)ws;                  // packed f16 weights+att
    _Float16* H1   = (_Float16*)(ws + 4194304);      //  4 MB [8192][256]
    _Float16* XLR0 = (_Float16*)(ws + 8388608);      // 32 MB [8192][2048]
    _Float16* GO0  = (_Float16*)(ws + 41943040);     // 16 MB [8192][1024]
    _Float16* XLR1 = (_Float16*)(ws + 58720256);     //  8 MB [8192][512]
    _Float16* GO1  = (_Float16*)(ws + 67108864);     //  4 MB [8192][256]

    _Float16* w_fus  = Wf16 + 0;         // [256][1024]
    _Float16* w_inp  = Wf16 + 262144;    // [256][256]
    _Float16* w_l0   = Wf16 + 327680;    // [2048][256] (wl|wr)
    _Float16* w_l1   = Wf16 + 851968;    // [512][1024] (wl|wr)
    _Float16* w_fp   = Wf16 + 1376256;   // [512][256]
    _Float16* att0_h = Wf16 + 1507328;   // [4][256] * log2e
    _Float16* att1_h = Wf16 + 1508352;   // [1][256] * log2e

    WTab t;
    const float* srcs[9] = {fusion_w, inproj_w, l0_wl, l0_wr, l1_wl, l1_wr,
                            fp_w, l0_att, l1_att};
    const int nel[9]  = {262144, 65536, 262144, 262144, 262144, 262144,
                         131072, 1024, 256};
    const int doff[9] = {0, 262144, 327680, 589824, 851968, 1114112,
                         1376256, 1507328, 1508352};
    const int sblk[10] = {0, 256, 320, 576, 832, 1088, 1344, 1472, 1473, 1474};
    for (int i = 0; i < 9; ++i) {
        t.src[i] = srcs[i]; t.nelem[i] = nel[i]; t.dstoff[i] = doff[i];
        t.scale[i] = (i >= 7) ? LOG2E : 1.0f;
    }
    for (int i = 0; i < 10; ++i) t.startblk[i] = sblk[i];

    // 1: weights fp32 -> f16 packed
    wconv_k<<<1474, 256, 0, stream>>>(t, Wf16);

    // 2: fusion + inproj fused -> H1
    fusion2_k<<<256, 512, 0, stream>>>(
        rgb, xm, w_fus, fusion_b, fusion_g, fusion_be,
        w_inp, inproj_b, norm_g, norm_b, H1);

    // 3: l0 GEMM -> XLR0 (xl|xr)
    gemm3_k<4, 4, 1><<<dim3(16, 64), 256, 0, stream>>>(
        H1, w_l0, l0_bl, l0_br, 1024, XLR0, 256, 2048);

    // 4: GAT h=4 (register-resident) -> GO0
    gat4_k<4, 2048, 1024, 1024><<<2048, 256, 0, stream>>>(
        XLR0, att0_h, l0_bias, GO0);

    // 5: l1 GEMM -> XLR1
    gemm3_k<2, 4, 1><<<dim3(4, 128), 256, 0, stream>>>(
        GO0, w_l1, l1_bl, l1_br, 256, XLR1, 1024, 512);

    // 6: GAT h=1 -> GO1
    gat4_k<1, 512, 256, 256><<<512, 256, 0, stream>>>(
        XLR1, att1_h, l1_bias, GO1);

    // 7: final -> planar [2, 512, 4096] fp32
    gemm3_k<2, 4, 2><<<dim3(4, 128), 256, 0, stream>>>(
        GO1, w_fp, fp_b, fp_b, 512, d_out, 256, 512);
}

// Round 16
// 116.750 us; speedup vs baseline: 1.0900x; 1.0333x over previous
//
#include <hip/hip_runtime.h>

// ---------------------------------------------------------------------------
// SegformerGAT round 16: REVERT to R12-validated kernels (BM=16 fusion
// abandoned after 3 fails; needs disasm to debug). Added: bijective XCD
// swizzle (T1) on gemm3/gat4 dispatches — pure block-id renaming, zero
// correctness risk (grids all % 8 == 0).
//  1 wconv  2 fusion2(BM=32, R12-exact)  3 gemm3 l0  4 gat4<4>  5 gemm3 l1
//  6 gat4<1>  7 gemm3 final
// ---------------------------------------------------------------------------

#define NNODE 4096
#define LN_EPS 1e-5f
#define LOG2E 1.4426950408889634f

typedef _Float16 half8 __attribute__((ext_vector_type(8)));
typedef _Float16 half4 __attribute__((ext_vector_type(4)));
typedef _Float16 h2 __attribute__((ext_vector_type(2)));
typedef float f32x4 __attribute__((ext_vector_type(4)));

__device__ __forceinline__ float wave_reduce_sum(float v) {
    #pragma unroll
    for (int off = 32; off > 0; off >>= 1) v += __shfl_xor(v, off, 64);
    return v;
}

__device__ __forceinline__ void gload_lds16(const void* g, void* l) {
    __builtin_amdgcn_global_load_lds(
        (const __attribute__((address_space(1))) void*)g,
        (__attribute__((address_space(3))) void*)l, 16, 0, 0);
}

template<int N> __device__ __forceinline__ void waitcnt_vm() {
    if constexpr (N <= 0)      asm volatile("s_waitcnt vmcnt(0)" ::: "memory");
    else if constexpr (N == 2) asm volatile("s_waitcnt vmcnt(2)" ::: "memory");
    else if constexpr (N == 3) asm volatile("s_waitcnt vmcnt(3)" ::: "memory");
    else if constexpr (N == 4) asm volatile("s_waitcnt vmcnt(4)" ::: "memory");
    else                       asm volatile("s_waitcnt vmcnt(8)" ::: "memory");
}
template<int N> __device__ __forceinline__ void waitcnt_vm_lgkm() {
    if constexpr (N <= 0)      asm volatile("s_waitcnt vmcnt(0) lgkmcnt(0)" ::: "memory");
    else if constexpr (N == 2) asm volatile("s_waitcnt vmcnt(2) lgkmcnt(0)" ::: "memory");
    else if constexpr (N == 3) asm volatile("s_waitcnt vmcnt(3) lgkmcnt(0)" ::: "memory");
    else                       asm volatile("s_waitcnt vmcnt(4) lgkmcnt(0)" ::: "memory");
}
__device__ __forceinline__ void barrier_raw() {
    asm volatile("s_barrier" ::: "memory");
}

// bijective XCD swizzle for grids with total % 8 == 0: XCD x gets the
// contiguous chunk [x*total/8, (x+1)*total/8) of original block ids.
__device__ __forceinline__ int xcd_swz(int lin, int total) {
    return (lin & 7) * (total >> 3) + (lin >> 3);
}

// ---------------------------------------------------------------------------
// 3-buffer counted-vmcnt MFMA f16 GEMM (R6/R7/R11/R12 validated) + XCD swizzle
// (block-id bijection only; tile math unchanged).
// OUTMODE: 1 = f16 [M,N] (swapped mfma); 2 = fp32 planar [B,N,4096].
// ---------------------------------------------------------------------------
template<int IT, int JT, int OUTMODE>
__global__ __launch_bounds__(256) void gemm3_k(
    const _Float16* __restrict__ A, const _Float16* __restrict__ W,
    const float* __restrict__ bias_lo, const float* __restrict__ bias_hi,
    int nsplit, void* __restrict__ Cout, int K, int N)
{
    constexpr int BM = 32 * IT, BN = 32 * JT;
    constexpr int CA = (BM * 4) / 256;
    constexpr int CB = (BN * 4) / 256;
    constexpr int L = CA + CB;
    __shared__ _Float16 ldsA[3][BM * 32];
    __shared__ _Float16 ldsB[3][BN * 32];

    const int tid = threadIdx.x;
    const int lin = blockIdx.y * gridDim.x + blockIdx.x;
    const int swz = xcd_swz(lin, gridDim.x * gridDim.y);
    const int m0 = (swz / gridDim.x) * BM, n0 = (swz % gridDim.x) * BN;
    const int lane = tid & 63, w = tid >> 6;
    const int fr = lane & 15, kq = lane >> 4;
    const int sq = (kq ^ (fr & 3)) * 8;
    const int wm = (w & 1) * (16 * IT), wn = (w >> 1) * (16 * JT);

    const _Float16* aP[CA]; int aC[CA];
    #pragma unroll
    for (int i = 0; i < CA; ++i) {
        const int c = i * 256 + tid, r = c >> 2, q = (c & 3) ^ (r & 3);
        aP[i] = A + (size_t)(m0 + r) * K + q * 8;
        aC[i] = c * 8;
    }
    const _Float16* bP[CB]; int bC[CB];
    #pragma unroll
    for (int i = 0; i < CB; ++i) {
        const int c = i * 256 + tid, r = c >> 2, q = (c & 3) ^ (r & 3);
        bP[i] = W + (size_t)(n0 + r) * K + q * 8;
        bC[i] = c * 8;
    }

    f32x4 acc[IT][JT] = {};
    const int NT = K >> 5;

    #pragma unroll
    for (int i = 0; i < CA; ++i) gload_lds16(aP[i], &ldsA[0][aC[i]]);
    #pragma unroll
    for (int i = 0; i < CB; ++i) gload_lds16(bP[i], &ldsB[0][bC[i]]);
    #pragma unroll
    for (int i = 0; i < CA; ++i) gload_lds16(aP[i] + 32, &ldsA[1][aC[i]]);
    #pragma unroll
    for (int i = 0; i < CB; ++i) gload_lds16(bP[i] + 32, &ldsB[1][bC[i]]);

    int bi = 0;
    for (int t = 0; t < NT; ++t) {
        if (t + 1 < NT) waitcnt_vm<L>(); else waitcnt_vm<0>();
        barrier_raw();
        if (t + 2 < NT) {
            int nb = bi + 2; if (nb >= 3) nb -= 3;
            const int k2 = (t + 2) << 5;
            #pragma unroll
            for (int i = 0; i < CA; ++i) gload_lds16(aP[i] + k2, &ldsA[nb][aC[i]]);
            #pragma unroll
            for (int i = 0; i < CB; ++i) gload_lds16(bP[i] + k2, &ldsB[nb][bC[i]]);
        }
        half8 af[IT], bf[JT];
        #pragma unroll
        for (int i = 0; i < IT; ++i)
            af[i] = *(const half8*)&ldsA[bi][(wm + i * 16 + fr) * 32 + sq];
        #pragma unroll
        for (int j = 0; j < JT; ++j)
            bf[j] = *(const half8*)&ldsB[bi][(wn + j * 16 + fr) * 32 + sq];
        #pragma unroll
        for (int i = 0; i < IT; ++i)
            #pragma unroll
            for (int j = 0; j < JT; ++j) {
                if (OUTMODE == 1)
                    acc[i][j] = __builtin_amdgcn_mfma_f32_16x16x32_f16(
                        bf[j], af[i], acc[i][j], 0, 0, 0);
                else
                    acc[i][j] = __builtin_amdgcn_mfma_f32_16x16x32_f16(
                        af[i], bf[j], acc[i][j], 0, 0, 0);
            }
        ++bi; if (bi == 3) bi = 0;
    }

    if (OUTMODE == 1) {
        // swapped: lane&15 = m, regs = 4 consecutive n
        #pragma unroll
        for (int i = 0; i < IT; ++i) {
            const int m = m0 + wm + i * 16 + fr;
            #pragma unroll
            for (int j = 0; j < JT; ++j) {
                const int nb4 = n0 + wn + j * 16 + kq * 4;
                const float* bp = (nb4 < nsplit) ? bias_lo + nb4
                                                 : bias_hi + (nb4 - nsplit);
                const float4 bv = *(const float4*)bp;
                half4 ov = {(_Float16)(acc[i][j][0] + bv.x),
                            (_Float16)(acc[i][j][1] + bv.y),
                            (_Float16)(acc[i][j][2] + bv.z),
                            (_Float16)(acc[i][j][3] + bv.w)};
                *(half4*)((_Float16*)Cout + (size_t)m * N + nb4) = ov;
            }
        }
    } else {
        // planar [B, N, 4096], float4 along node (m) dim
        #pragma unroll
        for (int j = 0; j < JT; ++j) {
            const int col = n0 + wn + j * 16 + fr;
            const float bc = (col < nsplit) ? bias_lo[col] : bias_hi[col - nsplit];
            #pragma unroll
            for (int i = 0; i < IT; ++i) {
                const int mrun = m0 + wm + i * 16 + kq * 4;
                const int b = mrun >> 12, node = mrun & 4095;
                float4 ov = {acc[i][j][0] + bc, acc[i][j][1] + bc,
                             acc[i][j][2] + bc, acc[i][j][3] + bc};
                *(float4*)((float*)Cout + ((size_t)(b * N + col)) * 4096 + node) = ov;
            }
        }
    }
}

// ---------------------------------------------------------------------------
// fusion2 (R12-exact, validated at 120.6 us): [concat(rgb,xm) @ W1^T + b1
// -> LN -> ReLU] in LDS, then [@ W2^T + b2 -> LN -> ReLU] -> out f16.
// BM=32, BN=256, 8 waves, 3-buffer counted-vmcnt pipelines.
// ---------------------------------------------------------------------------
__global__ __launch_bounds__(512) void fusion2_k(
    const float* __restrict__ A0, const float* __restrict__ A1,
    const _Float16* __restrict__ W1, const float* __restrict__ b1,
    const float* __restrict__ g1, const float* __restrict__ be1,
    const _Float16* __restrict__ W2, const float* __restrict__ b2,
    const float* __restrict__ g2, const float* __restrict__ be2,
    _Float16* __restrict__ out)
{
    __shared__ _Float16 lA[3][32 * 32];
    __shared__ _Float16 lB[3][256 * 32];
    __shared__ float lC[32 * 260];
    __shared__ _Float16 lH[8 * 1024];          // [t2][row*4+qslot][8]

    const int tid = threadIdx.x;               // 0..511
    const int m0 = blockIdx.x * 32;
    const int lane = tid & 63, w = tid >> 6;
    const int fr = lane & 15, kq = lane >> 4;
    const int sq = (kq ^ (fr & 3)) * 8;
    const int wr = (w & 1) * 16, wc = (w >> 1) * 64;
    const bool stager = (tid < 128);

    // phase-1 B staging (W1, K=1024): pre-swizzled source, linear gload dest
    const _Float16* bP[2]; int bC[2];
    #pragma unroll
    for (int i = 0; i < 2; ++i) {
        const int c = i * 512 + tid, r = c >> 2, q = (c & 3) ^ (r & 3);
        bP[i] = W1 + (size_t)r * 1024 + q * 8;
        bC[i] = c * 8;
    }
    // A staging (concat fp32, reg-staged; natural source quad, swizzled dest)
    const int ar = tid >> 2, aq = tid & 3;
    const int asw = (ar * 4 + (aq ^ (ar & 3))) * 8;
    float4 p0, p1;
    auto loadA = [&](int k) {
        const int gk = k + aq * 8;
        const float* s = (gk < 512) ? A0 + (size_t)(m0 + ar) * 512 + gk
                                    : A1 + (size_t)(m0 + ar) * 512 + gk - 512;
        p0 = *(const float4*)s;
        p1 = *(const float4*)(s + 4);
    };
    auto writeA = [&](int b) {
        half8 hv = {(_Float16)p0.x, (_Float16)p0.y, (_Float16)p0.z, (_Float16)p0.w,
                    (_Float16)p1.x, (_Float16)p1.y, (_Float16)p1.z, (_Float16)p1.w};
        *(half8*)&lA[b][asw] = hv;
    };

    f32x4 acc[4] = {};

    // ---- phase 1: K=1024, NT=32 ----
    if (stager) { loadA(0); writeA(0); loadA(32); }
    #pragma unroll
    for (int i = 0; i < 2; ++i) gload_lds16(bP[i], &lB[0][bC[i]]);
    #pragma unroll
    for (int i = 0; i < 2; ++i) gload_lds16(bP[i] + 32, &lB[1][bC[i]]);

    int bi = 0;
    for (int t = 0; t < 32; ++t) {
        if (t + 1 < 32) {
            if (stager) waitcnt_vm_lgkm<4>(); else waitcnt_vm_lgkm<2>();
        } else {
            waitcnt_vm_lgkm<0>();
        }
        barrier_raw();
        int nb1 = bi + 1; if (nb1 >= 3) nb1 -= 3;
        int nb2 = bi + 2; if (nb2 >= 3) nb2 -= 3;
        if (stager && t + 1 < 32) writeA(nb1);
        if (t + 2 < 32) {
            const int k2 = (t + 2) << 5;
            if (stager) loadA(k2);
            #pragma unroll
            for (int i = 0; i < 2; ++i) gload_lds16(bP[i] + k2, &lB[nb2][bC[i]]);
        }
        half8 af = *(const half8*)&lA[bi][(wr + fr) * 32 + sq];
        half8 bf[4];
        #pragma unroll
        for (int j = 0; j < 4; ++j)
            bf[j] = *(const half8*)&lB[bi][(wc + j * 16 + fr) * 32 + sq];
        #pragma unroll
        for (int j = 0; j < 4; ++j)
            acc[j] = __builtin_amdgcn_mfma_f32_16x16x32_f16(af, bf[j], acc[j], 0, 0, 0);
        ++bi; if (bi == 3) bi = 0;
    }

    // C1 -> lC (fp32 + b1)
    #pragma unroll
    for (int j = 0; j < 4; ++j) {
        const int col = wc + j * 16 + fr;
        const float bc = b1[col];
        #pragma unroll
        for (int r4 = 0; r4 < 4; ++r4)
            lC[(wr + kq * 4 + r4) * 260 + col] = acc[j][r4] + bc;
    }
    __syncthreads();

    // LN1 + ReLU -> lH (f16, gload-compatible swizzled tiles)
    {
        const float4 gv = *(const float4*)(g1 + lane * 4);
        const float4 bv = *(const float4*)(be1 + lane * 4);
        const int t2i = lane >> 3, gq = (lane >> 1) & 3, qo = (lane & 1) * 4;
        #pragma unroll
        for (int rr = 0; rr < 4; ++rr) {
            const int row = w * 4 + rr;
            const float4 v = *(const float4*)&lC[row * 260 + lane * 4];
            float s  = v.x + v.y + v.z + v.w;
            float s2 = v.x * v.x + v.y * v.y + v.z * v.z + v.w * v.w;
            s = wave_reduce_sum(s);
            s2 = wave_reduce_sum(s2);
            const float mu  = s * (1.0f / 256.0f);
            const float var = s2 * (1.0f / 256.0f) - mu * mu;
            const float rs  = rsqrtf(var + LN_EPS);
            half4 o;
            o[0] = (_Float16)fmaxf((v.x - mu) * rs * gv.x + bv.x, 0.f);
            o[1] = (_Float16)fmaxf((v.y - mu) * rs * gv.y + bv.y, 0.f);
            o[2] = (_Float16)fmaxf((v.z - mu) * rs * gv.z + bv.z, 0.f);
            o[3] = (_Float16)fmaxf((v.w - mu) * rs * gv.w + bv.w, 0.f);
            const int qslot = gq ^ (row & 3);
            *(half4*)&lH[t2i * 1024 + (row * 4 + qslot) * 8 + qo] = o;
        }
    }
    __syncthreads();

    // ---- phase 2: K=256, NT=8, A from lH ----
    const _Float16* b2P[2]; int b2C[2];
    #pragma unroll
    for (int i = 0; i < 2; ++i) {
        const int c = i * 512 + tid, r = c >> 2, q = (c & 3) ^ (r & 3);
        b2P[i] = W2 + (size_t)r * 256 + q * 8;
        b2C[i] = c * 8;
    }
    f32x4 acc2[4] = {};
    #pragma unroll
    for (int i = 0; i < 2; ++i) gload_lds16(b2P[i], &lB[0][b2C[i]]);
    #pragma unroll
    for (int i = 0; i < 2; ++i) gload_lds16(b2P[i] + 32, &lB[1][b2C[i]]);

    int bi2 = 0;
    for (int t2 = 0; t2 < 8; ++t2) {
        if (t2 + 1 < 8) waitcnt_vm<2>(); else waitcnt_vm<0>();
        barrier_raw();
        if (t2 + 2 < 8) {
            int nb = bi2 + 2; if (nb >= 3) nb -= 3;
            const int k2 = (t2 + 2) << 5;
            #pragma unroll
            for (int i = 0; i < 2; ++i) gload_lds16(b2P[i] + k2, &lB[nb][b2C[i]]);
        }
        const half8 af = *(const half8*)
            &lH[t2 * 1024 + ((wr + fr) * 4 + (kq ^ (fr & 3))) * 8];
        half8 bf[4];
        #pragma unroll
        for (int j = 0; j < 4; ++j)
            bf[j] = *(const half8*)&lB[bi2][(wc + j * 16 + fr) * 32 + sq];
        #pragma unroll
        for (int j = 0; j < 4; ++j)
            acc2[j] = __builtin_amdgcn_mfma_f32_16x16x32_f16(af, bf[j], acc2[j], 0, 0, 0);
        ++bi2; if (bi2 == 3) bi2 = 0;
    }

    // C2 -> lC (fp32 + b2)
    #pragma unroll
    for (int j = 0; j < 4; ++j) {
        const int col = wc + j * 16 + fr;
        const float bc = b2[col];
        #pragma unroll
        for (int r4 = 0; r4 < 4; ++r4)
            lC[(wr + kq * 4 + r4) * 260 + col] = acc2[j][r4] + bc;
    }
    __syncthreads();

    // LN2 + ReLU -> out (global f16)
    {
        const float4 gv = *(const float4*)(g2 + lane * 4);
        const float4 bv = *(const float4*)(be2 + lane * 4);
        #pragma unroll
        for (int rr = 0; rr < 4; ++rr) {
            const int row = w * 4 + rr;
            const float4 v = *(const float4*)&lC[row * 260 + lane * 4];
            float s  = v.x + v.y + v.z + v.w;
            float s2 = v.x * v.x + v.y * v.y + v.z * v.z + v.w * v.w;
            s = wave_reduce_sum(s);
            s2 = wave_reduce_sum(s2);
            const float mu  = s * (1.0f / 256.0f);
            const float var = s2 * (1.0f / 256.0f) - mu * mu;
            const float rs  = rsqrtf(var + LN_EPS);
            half4 o;
            o[0] = (_Float16)fmaxf((v.x - mu) * rs * gv.x + bv.x, 0.f);
            o[1] = (_Float16)fmaxf((v.y - mu) * rs * gv.y + bv.y, 0.f);
            o[2] = (_Float16)fmaxf((v.z - mu) * rs * gv.z + bv.z, 0.f);
            o[3] = (_Float16)fmaxf((v.w - mu) * rs * gv.w + bv.w, 0.f);
            *(half4*)(out + (size_t)(m0 + row) * 256 + lane * 4) = o;
        }
    }
}

// ---------------------------------------------------------------------------
// gat4 (R11/R12 validated) + XCD swizzle: register-resident GAT, no LDS.
// ---------------------------------------------------------------------------
template<int HEADS, int LD, int XROFF, int OC>
__global__ __launch_bounds__(256) void gat4_k(
    const _Float16* __restrict__ xlr, const _Float16* __restrict__ att16,
    const float* __restrict__ bias, _Float16* __restrict__ out)
{
    const int tid = threadIdx.x, wv = tid >> 6, lane = tid & 63;
    const int g = lane >> 4, li = lane & 15;
    const int blk = xcd_swz(blockIdx.x, gridDim.x);
    const int wid = blk * 4 + wv;
    const int gi = (HEADS == 4) ? wid : wid * 4 + g;
    const int h  = (HEADS == 4) ? g : 0;
    const int node = gi & (NNODE - 1);
    const int base = gi - node;
    const int nr = node >> 6, nc = node & 63;
    const int co = h * 256 + li * 16;

    int sidx[9]; float msk[9];
    {
        const int drs[8] = {-1,-1,-1, 0, 0, 1, 1, 1};
        const int dcs[8] = {-1, 0, 1,-1, 1,-1, 0, 1};
        #pragma unroll
        for (int j = 0; j < 8; ++j) {
            const int rj = nr + drs[j], cj = nc + dcs[j];
            const bool v = ((unsigned)rj < 64u) & ((unsigned)cj < 64u);
            sidx[j] = v ? (rj * 64 + cj) : node;
            msk[j] = v ? 0.f : -1e30f;
        }
        sidx[8] = node; msk[8] = 0.f;
    }

    const _Float16* xp = xlr + (size_t)base * LD + co;

    half8 x0[9], x1[9];
    #pragma unroll
    for (int j = 0; j < 9; ++j) {
        x0[j] = *(const half8*)(xp + (size_t)sidx[j] * LD);
        x1[j] = *(const half8*)(xp + (size_t)sidx[j] * LD + 8);
    }
    const half8 xr0 = *(const half8*)(xlr + (size_t)gi * LD + XROFF + co);
    const half8 xr1 = *(const half8*)(xlr + (size_t)gi * LD + XROFF + co + 8);
    const half8 at0 = *(const half8*)(att16 + h * 256 + li * 16);
    const half8 at1 = *(const half8*)(att16 + h * 256 + li * 16 + 8);
    const h2 hz = {(_Float16)0.f, (_Float16)0.f};
    const h2 c02 = {(_Float16)0.2f, (_Float16)0.2f};

    float lg[9];
    #pragma unroll
    for (int j = 0; j < 9; ++j) {
        h2 p = hz;
        #pragma unroll
        for (int k = 0; k < 4; ++k) {
            h2 e = ((const h2*)&x0[j])[k] + ((const h2*)&xr0)[k];
            h2 tt = __builtin_elementwise_fma(
                __builtin_elementwise_min(e, hz), c02,
                __builtin_elementwise_max(e, hz));
            p = __builtin_elementwise_fma(tt, ((const h2*)&at0)[k], p);
        }
        #pragma unroll
        for (int k = 0; k < 4; ++k) {
            h2 e = ((const h2*)&x1[j])[k] + ((const h2*)&xr1)[k];
            h2 tt = __builtin_elementwise_fma(
                __builtin_elementwise_min(e, hz), c02,
                __builtin_elementwise_max(e, hz));
            p = __builtin_elementwise_fma(tt, ((const h2*)&at1)[k], p);
        }
        float pl = (float)p[0] + (float)p[1];
        pl += __shfl_xor(pl, 1, 64);
        pl += __shfl_xor(pl, 2, 64);
        pl += __shfl_xor(pl, 4, 64);
        pl += __shfl_xor(pl, 8, 64);
        lg[j] = pl + msk[j];                 // log2-domain logits
    }

    float m = lg[0];
    #pragma unroll
    for (int j = 1; j < 9; ++j) m = fmaxf(m, lg[j]);
    float pj[9], z = 0.f;
    #pragma unroll
    for (int j = 0; j < 9; ++j) { pj[j] = __builtin_amdgcn_exp2f(lg[j] - m); z += pj[j]; }
    const float inv = __builtin_amdgcn_rcpf(z);

    float acc[16];
    #pragma unroll
    for (int k = 0; k < 16; ++k) acc[k] = 0.f;
    #pragma unroll
    for (int j = 0; j < 9; ++j) {
        const float wj = pj[j];
        #pragma unroll
        for (int k = 0; k < 8; ++k) acc[k]     += wj * (float)x0[j][k];
        #pragma unroll
        for (int k = 0; k < 8; ++k) acc[8 + k] += wj * (float)x1[j][k];
    }
    float bv[16];
    #pragma unroll
    for (int q = 0; q < 4; ++q) {
        const float4 b4 = *(const float4*)(bias + h * 256 + li * 16 + q * 4);
        bv[q * 4 + 0] = b4.x; bv[q * 4 + 1] = b4.y;
        bv[q * 4 + 2] = b4.z; bv[q * 4 + 3] = b4.w;
    }
    half8 o0, o1;
    #pragma unroll
    for (int k = 0; k < 8; ++k) o0[k] = (_Float16)fmaxf(acc[k] * inv + bv[k], 0.f);
    #pragma unroll
    for (int k = 0; k < 8; ++k) o1[k] = (_Float16)fmaxf(acc[8 + k] * inv + bv[8 + k], 0.f);
    *(half8*)(out + (size_t)gi * OC + co) = o0;
    *(half8*)(out + (size_t)gi * OC + co + 8) = o1;
}

// ---------------------------------------------------------------------------
// Weight/att conversion fp32 -> f16 packed (validated). att scaled log2e.
// ---------------------------------------------------------------------------
struct WTab {
    const float* src[9];
    int startblk[10];
    int nelem[9];
    int dstoff[9];
    float scale[9];
};

__global__ __launch_bounds__(256) void wconv_k(WTab t, _Float16* __restrict__ dst)
{
    const int b = blockIdx.x;
    int s = 0;
    #pragma unroll
    for (int i = 1; i < 9; ++i) s += (b >= t.startblk[i]);
    const int e0 = (b - t.startblk[s]) * 1024 + threadIdx.x * 4;
    if (e0 >= t.nelem[s]) return;
    const float4 v = *(const float4*)(t.src[s] + e0);
    const float sc = t.scale[s];
    half4 o = {(_Float16)(v.x * sc), (_Float16)(v.y * sc),
               (_Float16)(v.z * sc), (_Float16)(v.w * sc)};
    *(half4*)(dst + t.dstoff[s] + e0) = o;
}

// ---------------------------------------------------------------------------
extern "C" void kernel_launch(void* const* d_in, const int* in_sizes, int n_in,
                              void* d_out, int out_size, void* d_ws, size_t ws_size,
                              hipStream_t stream)
{
    const float* rgb       = (const float*)d_in[0];
    const float* xm        = (const float*)d_in[1];
    const float* fusion_w  = (const float*)d_in[3];
    const float* fusion_b  = (const float*)d_in[4];
    const float* fusion_g  = (const float*)d_in[5];
    const float* fusion_be = (const float*)d_in[6];
    const float* inproj_w  = (const float*)d_in[7];
    const float* inproj_b  = (const float*)d_in[8];
    const float* norm_g    = (const float*)d_in[9];
    const float* norm_b    = (const float*)d_in[10];
    const float* l0_wl     = (const float*)d_in[11];
    const float* l0_bl     = (const float*)d_in[12];
    const float* l0_wr     = (const float*)d_in[13];
    const float* l0_br     = (const float*)d_in[14];
    const float* l0_att    = (const float*)d_in[15];
    const float* l0_bias   = (const float*)d_in[16];
    const float* l1_wl     = (const float*)d_in[17];
    const float* l1_bl     = (const float*)d_in[18];
    const float* l1_wr     = (const float*)d_in[19];
    const float* l1_br     = (const float*)d_in[20];
    const float* l1_att    = (const float*)d_in[21];
    const float* l1_bias   = (const float*)d_in[22];
    const float* fp_w      = (const float*)d_in[23];
    const float* fp_b      = (const float*)d_in[24];

    // workspace (R7 layout)
    char* ws = (char*)d_ws;
    _Float16* Wf16 = (_Float16*)ws;                  // packed f16 weights+att
    _Float16* H1   = (_Float16*)(ws + 4194304);      //  4 MB [8192][256]
    _Float16* XLR0 = (_Float16*)(ws + 8388608);      // 32 MB [8192][2048]
    _Float16* GO0  = (_Float16*)(ws + 41943040);     // 16 MB [8192][1024]
    _Float16* XLR1 = (_Float16*)(ws + 58720256);     //  8 MB [8192][512]
    _Float16* GO1  = (_Float16*)(ws + 67108864);     //  4 MB [8192][256]

    _Float16* w_fus  = Wf16 + 0;         // [256][1024]
    _Float16* w_inp  = Wf16 + 262144;    // [256][256]
    _Float16* w_l0   = Wf16 + 327680;    // [2048][256] (wl|wr)
    _Float16* w_l1   = Wf16 + 851968;    // [512][1024] (wl|wr)
    _Float16* w_fp   = Wf16 + 1376256;   // [512][256]
    _Float16* att0_h = Wf16 + 1507328;   // [4][256] * log2e
    _Float16* att1_h = Wf16 + 1508352;   // [1][256] * log2e

    WTab t;
    const float* srcs[9] = {fusion_w, inproj_w, l0_wl, l0_wr, l1_wl, l1_wr,
                            fp_w, l0_att, l1_att};
    const int nel[9]  = {262144, 65536, 262144, 262144, 262144, 262144,
                         131072, 1024, 256};
    const int doff[9] = {0, 262144, 327680, 589824, 851968, 1114112,
                         1376256, 1507328, 1508352};
    const int sblk[10] = {0, 256, 320, 576, 832, 1088, 1344, 1472, 1473, 1474};
    for (int i = 0; i < 9; ++i) {
        t.src[i] = srcs[i]; t.nelem[i] = nel[i]; t.dstoff[i] = doff[i];
        t.scale[i] = (i >= 7) ? LOG2E : 1.0f;
    }
    for (int i = 0; i < 10; ++i) t.startblk[i] = sblk[i];

    // 1: weights fp32 -> f16 packed
    wconv_k<<<1474, 256, 0, stream>>>(t, Wf16);

    // 2: fusion + inproj fused -> H1  (R12-exact: 256 blocks, 512 thr)
    fusion2_k<<<256, 512, 0, stream>>>(
        rgb, xm, w_fus, fusion_b, fusion_g, fusion_be,
        w_inp, inproj_b, norm_g, norm_b, H1);

    // 3: l0 GEMM -> XLR0 (xl|xr)   (1024 blocks, XCD-swizzled)
    gemm3_k<4, 4, 1><<<dim3(16, 64), 256, 0, stream>>>(
        H1, w_l0, l0_bl, l0_br, 1024, XLR0, 256, 2048);

    // 4: GAT h=4 (register-resident) -> GO0   (2048 blocks, XCD-swizzled)
    gat4_k<4, 2048, 1024, 1024><<<2048, 256, 0, stream>>>(
        XLR0, att0_h, l0_bias, GO0);

    // 5: l1 GEMM -> XLR1   (512 blocks, XCD-swizzled)
    gemm3_k<2, 4, 1><<<dim3(4, 128), 256, 0, stream>>>(
        GO0, w_l1, l1_bl, l1_br, 256, XLR1, 1024, 512);

    // 6: GAT h=1 -> GO1   (512 blocks, XCD-swizzled)
    gat4_k<1, 512, 256, 256><<<512, 256, 0, stream>>>(
        XLR1, att1_h, l1_bias, GO1);

    // 7: final -> planar [2, 512, 4096] fp32   (512 blocks, XCD-swizzled)
    gemm3_k<2, 4, 2><<<dim3(4, 128), 256, 0, stream>>>(
        GO1, w_fp, fp_b, fp_b, 512, d_out, 256, 512);
}